// Round 5
// baseline (415.538 us; speedup 1.0000x reference)
//
#include <hip/hip_runtime.h>
#include <stdint.h>

typedef unsigned int u32;
typedef _Float16 f16_t;

typedef _Float16 f16x8 __attribute__((ext_vector_type(8)));
typedef __fp16   fp16x2 __attribute__((ext_vector_type(2)));
typedef float    f32x4 __attribute__((ext_vector_type(4)));

__device__ __forceinline__ f32x4 mfma16(f16x8 a, f16x8 b, f32x4 c){
  return __builtin_amdgcn_mfma_f32_16x16x32_f16(a, b, c, 0, 0, 0);
}
__device__ __forceinline__ float fexp2(float x){ return __builtin_amdgcn_exp2f(x); }
__device__ __forceinline__ u32 pkrtz(float a, float b){
  union { fp16x2 h; u32 u; } cv; cv.h = __builtin_amdgcn_cvt_pkrtz(a, b); return cv.u;
}

// async global->LDS, 16B per lane; LDS dest is wave-uniform base + lane*16
__device__ __forceinline__ void gl_lds16(const void* g, void* l){
  typedef const __attribute__((address_space(1))) void* gasp;
  typedef __attribute__((address_space(3))) void* lasp;
  gasp gp = reinterpret_cast<gasp>(reinterpret_cast<uintptr_t>(g));
  lasp lp = reinterpret_cast<lasp>(static_cast<u32>(reinterpret_cast<uintptr_t>(l)));
  __builtin_amdgcn_global_load_lds(gp, lp, 16, 0, 0);
}

// Stage a [NROWS][ROWB bytes] tile: LDS[row][c'] = G[row][c' ^ sw(row)].
// Swizzle mask adapts to row size: sw = (row & (ROWB/16-1)) << 4.
template<int NBYTES, int ROWB, int NT>
__device__ __forceinline__ void stage_swz(const char* gbase, u32 gstrideB, char* lds, int tid){
  const u32 lane = (u32)(tid & 63);
  #pragma unroll
  for (int j = 0; j < NBYTES/(NT*16); ++j){
    u32 o   = (u32)(j*NT + tid) * 16u;
    u32 row = o / (u32)ROWB;
    u32 col = (o % (u32)ROWB) ^ ((row & ((u32)(ROWB>>4)-1u)) << 4);
    gl_lds16(gbase + (size_t)row * gstrideB + col, lds + (o - lane*16u));
  }
}

template<int ROWB>
__device__ __forceinline__ u32 swzb(u32 row, u32 col){
  return col ^ ((row & ((u32)(ROWB>>4)-1u)) << 4);
}

template<int ROWB>
__device__ __forceinline__ f16x8 frag_ld(const char* lds, u32 row, u32 kbyte){
  return *reinterpret_cast<const f16x8*>(lds + (size_t)row*ROWB + swzb<ROWB>(row, kbyte));
}

// ---------------- prep: converts + mask bias + weight transposes, one launch ----------------
__device__ __forceinline__ void cvt8(const float* __restrict__ in, f16_t* __restrict__ out, u32 i){
  const f32x4* p = reinterpret_cast<const f32x4*>(in) + 2*(size_t)i;
  f32x4 a = p[0], b = p[1];
  f16x8 v;
  v[0]=(f16_t)a[0]; v[1]=(f16_t)a[1]; v[2]=(f16_t)a[2]; v[3]=(f16_t)a[3];
  v[4]=(f16_t)b[0]; v[5]=(f16_t)b[1]; v[6]=(f16_t)b[2]; v[7]=(f16_t)b[3];
  *(reinterpret_cast<f16x8*>(out) + i) = v;
}

__global__ void prep_all(const float* __restrict__ q, const float* __restrict__ k,
                         const float* __restrict__ v, const float* __restrict__ xr,
                         const int* __restrict__ mask, const int* __restrict__ rmask,
                         f16_t* __restrict__ qo, f16_t* __restrict__ ko,
                         f16_t* __restrict__ vo, f16_t* __restrict__ xo,
                         float* __restrict__ mb, float* __restrict__ rb,
                         const float* __restrict__ Wq, const float* __restrict__ Wk,
                         const float* __restrict__ Wv, const float* __restrict__ Wsk,
                         const float* __restrict__ Wsv, const float* __restrict__ Wo,
                         f16_t* __restrict__ wqT, f16_t* __restrict__ wkT, f16_t* __restrict__ wvT,
                         f16_t* __restrict__ wskT, f16_t* __restrict__ wsvT, f16_t* __restrict__ woT)
{
  __shared__ float tile[32][33];
  u32 b = blockIdx.x;
  if (b < 12288u){
    const float* in; f16_t* out; u32 base;
    if (b < 4096u){ in=q; out=qo; base=0u; }
    else if (b < 8192u){ in=k; out=ko; base=4096u; }
    else { in=v; out=vo; base=8192u; }
    cvt8(in, out, (b-base)*256u + threadIdx.x);
  } else if (b < 12800u){
    cvt8(xr, xo, (b-12288u)*256u + threadIdx.x);
  } else if (b < 12832u){
    u32 i = (b-12800u)*256u + threadIdx.x;
    int m = mask[i]; int r = rmask[i];
    mb[i] = m ? 0.0f : -1.0e9f;          // log2-domain bias: exp2(-1e9)=0
    rb[i] = (m && r) ? 0.0f : -1.0e9f;
  } else {
    u32 t = b - 12832u;
    const float* W; f16_t* WT; u32 K, N, i, j;
    if (t < 3072u){
      u32 w = t >> 10, l = t & 1023u;
      W = w==0 ? Wq : w==1 ? Wk : Wv;
      WT = w==0 ? wqT : w==1 ? wkT : wvT;
      K = 1024u; N = 1024u; i = l & 31u; j = l >> 5;
    } else if (t < 3328u){
      u32 l = t - 3072u;
      W  = l < 128u ? Wsk : Wsv;
      WT = l < 128u ? wskT : wsvT;
      l &= 127u;
      K = 1024u; N = 128u; i = l & 31u; j = l >> 5;
    } else {
      u32 l = t - 3328u;
      W = Wo; WT = woT; K = 1152u; N = 1024u; i = l % 36u; j = l / 36u;
    }
    const u32 k0 = i*32u, n0 = j*32u;
    const int tt = threadIdx.x;
    const int r = tt >> 3, c4 = (tt & 7) * 4;
    f32x4 val = *reinterpret_cast<const f32x4*>(W + (size_t)(k0 + r)*N + n0 + c4);
    tile[r][c4+0]=val[0]; tile[r][c4+1]=val[1]; tile[r][c4+2]=val[2]; tile[r][c4+3]=val[3];
    __syncthreads();
    union { f16_t x[4]; uint64_t u; } pk;
    #pragma unroll
    for (int jj=0;jj<4;++jj) pk.x[jj] = (f16_t)tile[c4+jj][r];
    *reinterpret_cast<uint64_t*>(WT + (size_t)(n0 + r)*K + k0 + c4) = pk.u;
  }
}

// ---------------- GEMM: C = A * B^T (+bias) ----------------
// mode 0: f32 out plain (swapped). mode 1: f16 head layout (swapped).
// mode 2: f16 VT layout ((m>>10)*ldc+n)*1024+(m&1023), pack along m (unswapped).
// mode 3: f16 plain (swapped).
struct GArg { const f16_t* A; const f16_t* Bt; const float* bias; void* C; u32 lda, ldb, ldc, K; int mode; };
struct GPack { GArg g[5]; int single; };

__global__ __launch_bounds__(256, 2)
void gemm_bt(GPack p)
{
  __shared__ char As[2][16384];
  __shared__ char Bs[2][16384];
  GArg g; u32 bn;
  const u32 bm = blockIdx.y * 128u;
  if (p.single >= 0){ g = p.g[p.single]; bn = blockIdx.x*128u; }
  else if (blockIdx.z == 0u){ if (blockIdx.x >= 2u) return; g = p.g[3u+blockIdx.x]; bn = 0u; }
  else { g = p.g[blockIdx.z-1u]; bn = blockIdx.x*128u; }

  const int tid = threadIdx.x, lane = tid & 63, wid = tid >> 6;
  const int wr = wid >> 1, wc = wid & 1;
  const char* Ab = (const char*)(g.A + (size_t)bm * g.lda);
  const char* Bb = (const char*)(g.Bt + (size_t)bn * g.ldb);
  const u32 ldaB = g.lda*2u, ldbB = g.ldb*2u;
  const bool swp = (g.mode != 2);

  f32x4 acc[4][4] = {};
  const int nt = (int)(g.K >> 6);

  stage_swz<16384,128,256>(Ab, ldaB, As[0], tid);
  stage_swz<16384,128,256>(Bb, ldbB, Bs[0], tid);
  __syncthreads();

  for (int t = 0; t < nt; ++t){
    if (t + 1 < nt){
      stage_swz<16384,128,256>(Ab + (size_t)(t+1)*128, ldaB, As[(t+1)&1], tid);
      stage_swz<16384,128,256>(Bb + (size_t)(t+1)*128, ldbB, Bs[(t+1)&1], tid);
    }
    const char* as = As[t&1]; const char* bs = Bs[t&1];
    f16x8 af[4][2], bf[4][2];
    #pragma unroll
    for (int mi=0; mi<4; ++mi)
      #pragma unroll
      for (int ks=0; ks<2; ++ks)
        af[mi][ks] = frag_ld<128>(as, (u32)(wr*64 + mi*16 + (lane&15)), (u32)(ks*64 + ((lane>>4)<<4)));
    #pragma unroll
    for (int ni=0; ni<4; ++ni)
      #pragma unroll
      for (int ks=0; ks<2; ++ks)
        bf[ni][ks] = frag_ld<128>(bs, (u32)(wc*64 + ni*16 + (lane&15)), (u32)(ks*64 + ((lane>>4)<<4)));
    if (swp){
      #pragma unroll
      for (int mi=0; mi<4; ++mi)
        #pragma unroll
        for (int ni=0; ni<4; ++ni)
          #pragma unroll
          for (int ks=0; ks<2; ++ks)
            acc[mi][ni] = mfma16(bf[ni][ks], af[mi][ks], acc[mi][ni]);
    } else {
      #pragma unroll
      for (int mi=0; mi<4; ++mi)
        #pragma unroll
        for (int ni=0; ni<4; ++ni)
          #pragma unroll
          for (int ks=0; ks<2; ++ks)
            acc[mi][ni] = mfma16(af[mi][ks], bf[ni][ks], acc[mi][ni]);
    }
    __syncthreads();
  }

  if (g.mode == 2){
    float bv[4];
    #pragma unroll
    for (int ni=0; ni<4; ++ni) bv[ni] = g.bias[bn + wc*64 + ni*16 + (lane&15)];
    f16_t* C = (f16_t*)g.C;
    #pragma unroll
    for (int mi=0; mi<4; ++mi){
      #pragma unroll
      for (int ni=0; ni<4; ++ni){
        u32 n  = bn + (u32)(wc*64 + ni*16 + (lane&15));
        u32 m0 = bm + (u32)(wr*64 + mi*16 + ((lane>>4)<<2));
        size_t idx0 = ((size_t)(m0>>10)*g.ldc + n)*1024 + (m0 & 1023);
        union { f16_t v[4]; uint64_t u; } pk;
        #pragma unroll
        for (int r=0;r<4;++r) pk.v[r] = (f16_t)(acc[mi][ni][r] + bv[ni]);
        *reinterpret_cast<uint64_t*>(C + idx0) = pk.u;
      }
    }
  } else {
    f32x4 bf4[4];
    #pragma unroll
    for (int ni=0; ni<4; ++ni)
      bf4[ni] = *reinterpret_cast<const f32x4*>(g.bias + bn + wc*64 + ni*16 + ((lane>>4)<<2));
    #pragma unroll
    for (int mi=0; mi<4; ++mi){
      u32 m = bm + (u32)(wr*64 + mi*16 + (lane&15));
      #pragma unroll
      for (int ni=0; ni<4; ++ni){
        u32 n0 = bn + (u32)(wc*64 + ni*16 + ((lane>>4)<<2));
        if (g.mode == 0){
          float* C = (float*)g.C;
          f32x4 v = acc[mi][ni] + bf4[ni];
          *reinterpret_cast<f32x4*>(C + (size_t)m*g.ldc + n0) = v;
        } else if (g.mode == 1){
          f16_t* C = (f16_t*)g.C;
          size_t idx = (((size_t)(m>>10)*16 + (n0>>6))*1024 + (m&1023))*64 + (n0&63);
          union { f16_t v[4]; uint64_t u; } pk;
          #pragma unroll
          for (int r=0;r<4;++r) pk.v[r] = (f16_t)(acc[mi][ni][r] + bf4[ni][r]);
          *reinterpret_cast<uint64_t*>(C + idx) = pk.u;
        } else {
          f16_t* C = (f16_t*)g.C;
          union { f16_t v[4]; uint64_t u; } pk;
          #pragma unroll
          for (int r=0;r<4;++r) pk.v[r] = (f16_t)(acc[mi][ni][r] + bf4[ni][r]);
          *reinterpret_cast<uint64_t*>(C + (size_t)m*g.ldc + n0) = pk.u;
        }
      }
    }
  }
}

// ---------------- attention pass 1: row sums of exp2 (fixed-max softmax) ----------------
// Wave owns 16 q-rows x full k-chunk. Lane: ql=lane&15 (q), h=lane>>4 (k subgroup).
template<int D, int KCH, int BSHIFT, int SCALEBIT>
__device__ __forceinline__ void pass1_body(char* smem,
    const f16_t* __restrict__ Qg, const f16_t* __restrict__ Kg,
    const float* __restrict__ mbias, float* __restrict__ statR,
    const int tid, const u32 qt, const u32 batch)
{
  constexpr int S = 1024;
  constexpr int ROWB = D*2;
  constexpr int MI = KCH/16;
  constexpr int KSL = D/32;
  char* Qs  = smem;
  char* Ks0 = smem + 128*ROWB;
  char* Ks1 = Ks0 + KCH*ROWB;

  const int lane = tid & 63, wq = tid >> 6;
  const int ql = lane & 15, h = lane >> 4;
  const float scale = SCALEBIT ? 0.1803368801111244f : 1.4426950408889634f;
  const f16_t* qb = Qg + ((size_t)batch*S + (size_t)qt*128)*D;
  const f16_t* kb = Kg + (size_t)batch*S*D;
  const float* mbb = mbias + (size_t)(batch >> BSHIFT)*S;

  stage_swz<128*ROWB, ROWB, 512>((const char*)qb, ROWB, Qs, tid);
  stage_swz<KCH*ROWB, ROWB, 512>((const char*)kb, ROWB, Ks0, tid);
  __syncthreads();

  float sacc = 0.0f;
  constexpr int NCH = S / KCH;
  for (int ch = 0; ch < NCH; ++ch){
    if (ch + 1 < NCH)
      stage_swz<KCH*ROWB, ROWB, 512>((const char*)(kb + (size_t)(ch+1)*KCH*D), ROWB, ((ch+1)&1)?Ks1:Ks0, tid);
    const char* ks = (ch&1) ? Ks1 : Ks0;

    f32x4 acc[MI] = {};
    #pragma unroll
    for (int ksl=0; ksl<KSL; ++ksl){
      f16x8 bf = frag_ld<ROWB>(Qs, (u32)(wq*16 + ql), (u32)(ksl*64 + h*16));
      #pragma unroll
      for (int mi=0; mi<MI; ++mi){
        f16x8 af = frag_ld<ROWB>(ks, (u32)(mi*16 + ql), (u32)(ksl*64 + h*16));
        acc[mi] = mfma16(af, bf, acc[mi]);
      }
    }
    #pragma unroll
    for (int mi=0; mi<MI; ++mi){
      f32x4 mb = *reinterpret_cast<const f32x4*>(mbb + ch*KCH + mi*16 + h*4);
      #pragma unroll
      for (int r=0;r<4;++r) sacc += fexp2(acc[mi][r]*scale + mb[r]);
    }
    __syncthreads();
  }

  sacc += __shfl_xor(sacc, 16);
  sacc += __shfl_xor(sacc, 32);
  if (lane < 16)
    statR[(size_t)batch*S + (size_t)qt*128 + (size_t)(wq*16) + (u32)ql] = 1.0f / sacc;
}

// ---------------- attention pass 2: direct softmax store + in-register PV ----------------
template<int D, int KCH, int BSHIFT, int SCALEBIT>
__device__ __forceinline__ void pass2_body(char* smem,
    const f16_t* __restrict__ Qg, const f16_t* __restrict__ Kg, const f16_t* __restrict__ Vtg,
    const float* __restrict__ mbias, const float* __restrict__ statR,
    float* __restrict__ attnOut, f16_t* __restrict__ xout, u32 xld, u32 xcolAdd,
    const int tid, const u32 qt, const u32 batch)
{
  constexpr int S = 1024;
  constexpr int ROWB  = D*2;
  constexpr int ROWBV = KCH*2;
  constexpr int MI   = KCH/16;   // k-token 16-blocks in chunk
  constexpr int KSL  = D/32;     // QK contraction slices
  constexpr int PSL  = KCH/32;   // PV contraction slices
  constexpr int MIPV = D/16;     // d 16-blocks
  char* Qs  = smem;
  char* Ks0 = Qs + 128*ROWB;
  char* Ks1 = Ks0 + KCH*ROWB;
  char* Vs0 = Ks1 + KCH*ROWB;
  char* Vs1 = Vs0 + D*ROWBV;

  const int lane = tid & 63, wq = tid >> 6;
  const int ql = lane & 15, h = lane >> 4;
  const u32 bb = batch >> BSHIFT;
  const float scale = SCALEBIT ? 0.1803368801111244f : 1.4426950408889634f;
  const f16_t* qb = Qg + ((size_t)batch*S + (size_t)qt*128)*D;
  const f16_t* kb = Kg + (size_t)batch*S*D;
  const char* vtb = (const char*)(Vtg + (size_t)batch*D*S);
  const float* mbb = mbias + (size_t)bb*S;

  const u32 q = qt*128u + (u32)(wq*16 + ql);
  const float rreg = statR[(size_t)batch*S + q];
  float* arow = attnOut + (size_t)batch*S*S + (size_t)q*S;
  f32x4 accX[MIPV] = {};

  stage_swz<128*ROWB, ROWB, 512>((const char*)qb, ROWB, Qs, tid);
  stage_swz<KCH*ROWB, ROWB, 512>((const char*)kb, ROWB, Ks0, tid);
  stage_swz<D*ROWBV, ROWBV, 512>(vtb, (u32)(S*2), Vs0, tid);
  __syncthreads();

  // bpermute base index (bytes): src lane = ql + 16*((2h + b)&3), b from s>>1
  const int bidx = ((ql | ((h & 1) << 5)) << 2);

  constexpr int NCH = S / KCH;
  for (int ch = 0; ch < NCH; ++ch){
    if (ch + 1 < NCH){
      stage_swz<KCH*ROWB, ROWB, 512>((const char*)(kb + (size_t)(ch+1)*KCH*D), ROWB, ((ch+1)&1)?Ks1:Ks0, tid);
      stage_swz<D*ROWBV, ROWBV, 512>(vtb + (size_t)(ch+1)*KCH*2, (u32)(S*2), ((ch+1)&1)?Vs1:Vs0, tid);
    }
    const char* ks = (ch&1) ? Ks1 : Ks0;
    const char* vs = (ch&1) ? Vs1 : Vs0;

    // QK^T: C[k-token][q], lane holds k = mi*16 + 4h + r for its fixed q
    f32x4 acc[MI] = {};
    #pragma unroll
    for (int ksl=0; ksl<KSL; ++ksl){
      f16x8 bf = frag_ld<ROWB>(Qs, (u32)(wq*16 + ql), (u32)(ksl*64 + h*16));
      #pragma unroll
      for (int mi=0; mi<MI; ++mi){
        f16x8 af = frag_ld<ROWB>(ks, (u32)(mi*16 + ql), (u32)(ksl*64 + h*16));
        acc[mi] = mfma16(af, bf, acc[mi]);
      }
    }

    // softmax -> direct global store (nontemporal) + pack to f16 pairs
    u32 pk[MI][2];
    #pragma unroll
    for (int mi=0; mi<MI; ++mi){
      f32x4 mb = *reinterpret_cast<const f32x4*>(mbb + ch*KCH + mi*16 + h*4);
      f32x4 pv;
      #pragma unroll
      for (int r=0;r<4;++r)
        pv[r] = fexp2(acc[mi][r]*scale + mb[r]) * rreg;
      __builtin_nontemporal_store(pv, reinterpret_cast<f32x4*>(arow + ch*KCH + mi*16 + h*4));
      pk[mi][0] = pkrtz(pv[0], pv[1]);
      pk[mi][1] = pkrtz(pv[2], pv[3]);
    }

    // PV: build B-frag (rows=q, k = psl*32 + 8h + j) via 2x bpermute + select
    #pragma unroll
    for (int psl=0; psl<PSL; ++psl){
      union { u32 w[4]; f16x8 v; } pb;
      #pragma unroll
      for (int s=0; s<4; ++s){
        int ii = bidx + ((s & 2) ? 64 : 0);
        u32 pa  = (u32)__builtin_amdgcn_ds_bpermute(ii, (int)pk[2*psl][s&1]);
        u32 pbv = (u32)__builtin_amdgcn_ds_bpermute(ii, (int)pk[2*psl+1][s&1]);
        pb.w[s] = (lane & 32) ? pbv : pa;
      }
      #pragma unroll
      for (int mi2=0; mi2<MIPV; ++mi2){
        f16x8 vf = frag_ld<ROWBV>(vs, (u32)(mi2*16 + ql), (u32)(psl*64 + h*16));
        accX[mi2] = mfma16(vf, pb.v, accX[mi2]);
      }
    }
    __syncthreads();
  }

  // write x^T to concat buffer: accX[mi2][r] = x[d = mi2*16+4h+r][q]
  u32 col0 = (batch & ((1u<<BSHIFT)-1u)) * (u32)D + xcolAdd;
  #pragma unroll
  for (int mi2=0; mi2<MIPV; ++mi2){
    union { f16_t v[4]; uint64_t u; } pk4;
    #pragma unroll
    for (int r=0;r<4;++r) pk4.v[r] = (f16_t)accX[mi2][r];
    *reinterpret_cast<uint64_t*>(xout + ((size_t)bb*S + q)*xld + col0 + mi2*16 + h*4) = pk4.u;
  }
}

// ---------------- combined attention kernels (rsa blocks dispatched first) ----------------
__global__ __launch_bounds__(512, 4)
void attn_pass1_all(const f16_t* __restrict__ Qh, const f16_t* __restrict__ Kh,
                    const float* __restrict__ mbias, float* __restrict__ stRm,
                    const f16_t* __restrict__ xrf, const f16_t* __restrict__ strK,
                    const float* __restrict__ rbias, float* __restrict__ stRr)
{
  __shared__ char smem[49152];
  const int tid = threadIdx.x;
  const u32 qt = blockIdx.x, y = blockIdx.y;
  if (y < 8u) pass1_body<128,32,0,0>(smem, xrf, strK, rbias, stRr, tid, qt, y);
  else        pass1_body<64, 64,4,1>(smem, Qh,  Kh,   mbias, stRm, tid, qt, y-8u);
}

__global__ __launch_bounds__(512, 4)
void attn_pass2_all(const f16_t* __restrict__ Qh, const f16_t* __restrict__ Kh,
                    const f16_t* __restrict__ Vth, const float* __restrict__ mbias,
                    const float* __restrict__ stRm, float* __restrict__ attnp,
                    const f16_t* __restrict__ xrf, const f16_t* __restrict__ strK,
                    const f16_t* __restrict__ strVt, const float* __restrict__ rbias,
                    const float* __restrict__ stRr, float* __restrict__ rsap,
                    f16_t* __restrict__ conc)
{
  __shared__ char smem[65536];
  const int tid = threadIdx.x;
  const u32 qt = blockIdx.x, y = blockIdx.y;
  if (y < 8u) pass2_body<128,32,0,0>(smem, xrf, strK, strVt, rbias, stRr, rsap, conc, 1152u, 1024u, tid, qt, y);
  else        pass2_body<64, 64,4,1>(smem, Qh,  Kh,   Vth,   mbias, stRm, attnp, conc, 1152u, 0u,    tid, qt, y-8u);
}

// ---------------- launch ----------------
extern "C" void kernel_launch(void* const* d_in, const int* in_sizes, int n_in,
                              void* d_out, int out_size, void* d_ws, size_t ws_size,
                              hipStream_t stream)
{
  const float* query = (const float*)d_in[0];
  const float* key   = (const float*)d_in[1];
  const float* value = (const float*)d_in[2];
  const float* x_rsa = (const float*)d_in[3];
  const int*   mask  = (const int*)d_in[4];
  const int*   rmask = (const int*)d_in[5];
  const float* Wq = (const float*)d_in[6];  const float* bq = (const float*)d_in[7];
  const float* Wk = (const float*)d_in[8];  const float* bk = (const float*)d_in[9];
  const float* Wv = (const float*)d_in[10]; const float* bv = (const float*)d_in[11];
  const float* Wsk= (const float*)d_in[12]; const float* bsk= (const float*)d_in[13];
  const float* Wsv= (const float*)d_in[14]; const float* bsv= (const float*)d_in[15];
  const float* Wo = (const float*)d_in[16]; const float* bo = (const float*)d_in[17];

  char* ws = (char*)d_ws;
  size_t off = 0;
  auto alloc = [&](size_t bytes)->char*{ char* p = ws + off; off += (bytes + 255) & ~(size_t)255; return p; };

  f16_t* q16  = (f16_t*)alloc(16777216);
  f16_t* k16  = (f16_t*)alloc(16777216);
  f16_t* v16  = (f16_t*)alloc(16777216);
  f16_t* xrf  = (f16_t*)alloc(2097152);
  f16_t* wqT  = (f16_t*)alloc(2097152);
  f16_t* wkT  = (f16_t*)alloc(2097152);
  f16_t* wvT  = (f16_t*)alloc(2097152);
  f16_t* wskT = (f16_t*)alloc(262144);
  f16_t* wsvT = (f16_t*)alloc(262144);
  f16_t* woT  = (f16_t*)alloc(2359296);
  f16_t* Qh   = (f16_t*)alloc(16777216);
  f16_t* Kh   = (f16_t*)alloc(16777216);
  f16_t* Vth  = (f16_t*)alloc(16777216);
  f16_t* strK = (f16_t*)alloc(2097152);
  f16_t* strVt= (f16_t*)alloc(2097152);
  f16_t* conc = (f16_t*)alloc(18874368);
  float* stRm = (float*)alloc(524288);
  float* stRr = (float*)alloc(32768);
  float* mbias= (float*)alloc(32768);
  float* rbias= (float*)alloc(32768);

  // prep: converts + mask biases + weight transposes, one launch
  prep_all<<<17312,256,0,stream>>>(query, key, value, x_rsa, mask, rmask,
                                   q16, k16, v16, xrf, mbias, rbias,
                                   Wq, Wk, Wv, Wsk, Wsv, Wo,
                                   wqT, wkT, wvT, wskT, wsvT, woT);

  // all input projections in one launch: z=0 -> str (bx 0/1), z=1..3 -> Q/K/V
  {
    GPack pm{};
    pm.g[0] = {q16, wqT,  bq,  (void*)Qh,    1024u,1024u,0u,   1024u, 1};
    pm.g[1] = {k16, wkT,  bk,  (void*)Kh,    1024u,1024u,0u,   1024u, 1};
    pm.g[2] = {v16, wvT,  bv,  (void*)Vth,   1024u,1024u,1024u,1024u, 2};
    pm.g[3] = {k16, wskT, bsk, (void*)strK,  1024u,1024u,128u, 1024u, 3};
    pm.g[4] = {v16, wsvT, bsv, (void*)strVt, 1024u,1024u,128u, 1024u, 2};
    pm.single = -1;
    gemm_bt<<<dim3(8,64,4),256,0,stream>>>(pm);
  }

  float* outp  = (float*)d_out;
  float* attnp = outp + 8388608;
  float* rsap  = outp + 8388608 + 134217728;

  // attention stats (rsa y<8 first, then main)
  attn_pass1_all<<<dim3(8,136),512,0,stream>>>(Qh, Kh, mbias, stRm, xrf, strK, rbias, stRr);

  // attention pass2 (softmax direct store + in-register PV into concat)
  attn_pass2_all<<<dim3(8,136),512,0,stream>>>(Qh, Kh, Vth, mbias, stRm, attnp,
                                               xrf, strK, strVt, rbias, stRr, rsap, conc);

  // output projection
  {
    GPack po{};
    po.g[0] = {conc, woT, bo, (void*)outp, 1152u,1152u,1024u,1152u, 0};
    po.g[1] = po.g[0]; po.g[2] = po.g[0]; po.g[3] = po.g[0]; po.g[4] = po.g[0];
    po.single = 0;
    gemm_bt<<<dim3(8,64,1),256,0,stream>>>(po);
  }

  (void)in_sizes; (void)n_in; (void)out_size; (void)ws_size;
}

// Round 6
// 407.510 us; speedup vs baseline: 1.0197x; 1.0197x over previous
//
#include <hip/hip_runtime.h>
#include <stdint.h>

typedef unsigned int u32;
typedef _Float16 f16_t;

typedef _Float16 f16x8 __attribute__((ext_vector_type(8)));
typedef __fp16   fp16x2 __attribute__((ext_vector_type(2)));
typedef float    f32x4 __attribute__((ext_vector_type(4)));

__device__ __forceinline__ f32x4 mfma16(f16x8 a, f16x8 b, f32x4 c){
  return __builtin_amdgcn_mfma_f32_16x16x32_f16(a, b, c, 0, 0, 0);
}
__device__ __forceinline__ float fexp2(float x){ return __builtin_amdgcn_exp2f(x); }
__device__ __forceinline__ u32 pkrtz(float a, float b){
  union { fp16x2 h; u32 u; } cv; cv.h = __builtin_amdgcn_cvt_pkrtz(a, b); return cv.u;
}

// barrier that drains staging loads but leaves the N newest VMEM ops (stores) in flight
template<int N>
__device__ __forceinline__ void barrier_vmleave(){
  asm volatile("s_waitcnt vmcnt(%0)" :: "i"(N) : "memory");
  __builtin_amdgcn_s_barrier();
}

// async global->LDS, 16B per lane; LDS dest is wave-uniform base + lane*16
__device__ __forceinline__ void gl_lds16(const void* g, void* l){
  typedef const __attribute__((address_space(1))) void* gasp;
  typedef __attribute__((address_space(3))) void* lasp;
  gasp gp = reinterpret_cast<gasp>(reinterpret_cast<uintptr_t>(g));
  lasp lp = reinterpret_cast<lasp>(static_cast<u32>(reinterpret_cast<uintptr_t>(l)));
  __builtin_amdgcn_global_load_lds(gp, lp, 16, 0, 0);
}

// Stage a [NROWS][ROWB bytes] tile: LDS[row][c'] = G[row][c' ^ sw(row)].
// Swizzle mask adapts to row size: sw = (row & (ROWB/16-1)) << 4.
template<int NBYTES, int ROWB, int NT>
__device__ __forceinline__ void stage_swz(const char* gbase, u32 gstrideB, char* lds, int tid){
  const u32 lane = (u32)(tid & 63);
  #pragma unroll
  for (int j = 0; j < NBYTES/(NT*16); ++j){
    u32 o   = (u32)(j*NT + tid) * 16u;
    u32 row = o / (u32)ROWB;
    u32 col = (o % (u32)ROWB) ^ ((row & ((u32)(ROWB>>4)-1u)) << 4);
    gl_lds16(gbase + (size_t)row * gstrideB + col, lds + (o - lane*16u));
  }
}

template<int ROWB>
__device__ __forceinline__ u32 swzb(u32 row, u32 col){
  return col ^ ((row & ((u32)(ROWB>>4)-1u)) << 4);
}

template<int ROWB>
__device__ __forceinline__ f16x8 frag_ld(const char* lds, u32 row, u32 kbyte){
  return *reinterpret_cast<const f16x8*>(lds + (size_t)row*ROWB + swzb<ROWB>(row, kbyte));
}

// ---------------- prep: converts + mask bias + weight transposes, one launch ----------------
__device__ __forceinline__ void cvt8(const float* __restrict__ in, f16_t* __restrict__ out, u32 i){
  const f32x4* p = reinterpret_cast<const f32x4*>(in) + 2*(size_t)i;
  f32x4 a = p[0], b = p[1];
  f16x8 v;
  v[0]=(f16_t)a[0]; v[1]=(f16_t)a[1]; v[2]=(f16_t)a[2]; v[3]=(f16_t)a[3];
  v[4]=(f16_t)b[0]; v[5]=(f16_t)b[1]; v[6]=(f16_t)b[2]; v[7]=(f16_t)b[3];
  *(reinterpret_cast<f16x8*>(out) + i) = v;
}

__global__ void prep_all(const float* __restrict__ q, const float* __restrict__ k,
                         const float* __restrict__ v, const float* __restrict__ xr,
                         const int* __restrict__ mask, const int* __restrict__ rmask,
                         f16_t* __restrict__ qo, f16_t* __restrict__ ko,
                         f16_t* __restrict__ vo, f16_t* __restrict__ xo,
                         float* __restrict__ mb, float* __restrict__ rb,
                         const float* __restrict__ Wq, const float* __restrict__ Wk,
                         const float* __restrict__ Wv, const float* __restrict__ Wsk,
                         const float* __restrict__ Wsv, const float* __restrict__ Wo,
                         f16_t* __restrict__ wqT, f16_t* __restrict__ wkT, f16_t* __restrict__ wvT,
                         f16_t* __restrict__ wskT, f16_t* __restrict__ wsvT, f16_t* __restrict__ woT)
{
  __shared__ float tile[32][33];
  u32 b = blockIdx.x;
  if (b < 12288u){
    const float* in; f16_t* out; u32 base;
    if (b < 4096u){ in=q; out=qo; base=0u; }
    else if (b < 8192u){ in=k; out=ko; base=4096u; }
    else { in=v; out=vo; base=8192u; }
    cvt8(in, out, (b-base)*256u + threadIdx.x);
  } else if (b < 12800u){
    cvt8(xr, xo, (b-12288u)*256u + threadIdx.x);
  } else if (b < 12832u){
    u32 i = (b-12800u)*256u + threadIdx.x;
    int m = mask[i]; int r = rmask[i];
    mb[i] = m ? 0.0f : -1.0e9f;          // log2-domain bias: exp2(-1e9)=0
    rb[i] = (m && r) ? 0.0f : -1.0e9f;
  } else {
    u32 t = b - 12832u;
    const float* W; f16_t* WT; u32 K, N, i, j;
    if (t < 3072u){
      u32 w = t >> 10, l = t & 1023u;
      W = w==0 ? Wq : w==1 ? Wk : Wv;
      WT = w==0 ? wqT : w==1 ? wkT : wvT;
      K = 1024u; N = 1024u; i = l & 31u; j = l >> 5;
    } else if (t < 3328u){
      u32 l = t - 3072u;
      W  = l < 128u ? Wsk : Wsv;
      WT = l < 128u ? wskT : wsvT;
      l &= 127u;
      K = 1024u; N = 128u; i = l & 31u; j = l >> 5;
    } else {
      u32 l = t - 3328u;
      W = Wo; WT = woT; K = 1152u; N = 1024u; i = l % 36u; j = l / 36u;
    }
    const u32 k0 = i*32u, n0 = j*32u;
    const int tt = threadIdx.x;
    const int r = tt >> 3, c4 = (tt & 7) * 4;
    f32x4 val = *reinterpret_cast<const f32x4*>(W + (size_t)(k0 + r)*N + n0 + c4);
    tile[r][c4+0]=val[0]; tile[r][c4+1]=val[1]; tile[r][c4+2]=val[2]; tile[r][c4+3]=val[3];
    __syncthreads();
    union { f16_t x[4]; uint64_t u; } pk;
    #pragma unroll
    for (int jj=0;jj<4;++jj) pk.x[jj] = (f16_t)tile[c4+jj][r];
    *reinterpret_cast<uint64_t*>(WT + (size_t)(n0 + r)*K + k0 + c4) = pk.u;
  }
}

// ---------------- GEMM: C = A * B^T (+bias) ----------------
// mode 0: f32 out plain (swapped). mode 1: f16 head layout (swapped).
// mode 2: f16 VT layout ((m>>10)*ldc+n)*1024+(m&1023), pack along m (unswapped).
// mode 3: f16 plain (swapped).
struct GArg { const f16_t* A; const f16_t* Bt; const float* bias; void* C; u32 lda, ldb, ldc, K; int mode; };
struct GPack { GArg g[5]; int single; };

__global__ __launch_bounds__(256, 2)
void gemm_bt(GPack p)
{
  __shared__ char As[2][16384];
  __shared__ char Bs[2][16384];
  GArg g; u32 bn;
  const u32 bm = blockIdx.y * 128u;
  if (p.single >= 0){ g = p.g[p.single]; bn = blockIdx.x*128u; }
  else if (blockIdx.z == 0u){ if (blockIdx.x >= 2u) return; g = p.g[3u+blockIdx.x]; bn = 0u; }
  else { g = p.g[blockIdx.z-1u]; bn = blockIdx.x*128u; }

  const int tid = threadIdx.x, lane = tid & 63, wid = tid >> 6;
  const int wr = wid >> 1, wc = wid & 1;
  const char* Ab = (const char*)(g.A + (size_t)bm * g.lda);
  const char* Bb = (const char*)(g.Bt + (size_t)bn * g.ldb);
  const u32 ldaB = g.lda*2u, ldbB = g.ldb*2u;
  const bool swp = (g.mode != 2);

  f32x4 acc[4][4] = {};
  const int nt = (int)(g.K >> 6);

  stage_swz<16384,128,256>(Ab, ldaB, As[0], tid);
  stage_swz<16384,128,256>(Bb, ldbB, Bs[0], tid);
  __syncthreads();

  for (int t = 0; t < nt; ++t){
    if (t + 1 < nt){
      stage_swz<16384,128,256>(Ab + (size_t)(t+1)*128, ldaB, As[(t+1)&1], tid);
      stage_swz<16384,128,256>(Bb + (size_t)(t+1)*128, ldbB, Bs[(t+1)&1], tid);
    }
    const char* as = As[t&1]; const char* bs = Bs[t&1];
    f16x8 af[4][2], bf[4][2];
    #pragma unroll
    for (int mi=0; mi<4; ++mi)
      #pragma unroll
      for (int ks=0; ks<2; ++ks)
        af[mi][ks] = frag_ld<128>(as, (u32)(wr*64 + mi*16 + (lane&15)), (u32)(ks*64 + ((lane>>4)<<4)));
    #pragma unroll
    for (int ni=0; ni<4; ++ni)
      #pragma unroll
      for (int ks=0; ks<2; ++ks)
        bf[ni][ks] = frag_ld<128>(bs, (u32)(wc*64 + ni*16 + (lane&15)), (u32)(ks*64 + ((lane>>4)<<4)));
    if (swp){
      #pragma unroll
      for (int mi=0; mi<4; ++mi)
        #pragma unroll
        for (int ni=0; ni<4; ++ni)
          #pragma unroll
          for (int ks=0; ks<2; ++ks)
            acc[mi][ni] = mfma16(bf[ni][ks], af[mi][ks], acc[mi][ni]);
    } else {
      #pragma unroll
      for (int mi=0; mi<4; ++mi)
        #pragma unroll
        for (int ni=0; ni<4; ++ni)
          #pragma unroll
          for (int ks=0; ks<2; ++ks)
            acc[mi][ni] = mfma16(af[mi][ks], bf[ni][ks], acc[mi][ni]);
    }
    __syncthreads();
  }

  if (g.mode == 2){
    float bv[4];
    #pragma unroll
    for (int ni=0; ni<4; ++ni) bv[ni] = g.bias[bn + wc*64 + ni*16 + (lane&15)];
    f16_t* C = (f16_t*)g.C;
    #pragma unroll
    for (int mi=0; mi<4; ++mi){
      #pragma unroll
      for (int ni=0; ni<4; ++ni){
        u32 n  = bn + (u32)(wc*64 + ni*16 + (lane&15));
        u32 m0 = bm + (u32)(wr*64 + mi*16 + ((lane>>4)<<2));
        size_t idx0 = ((size_t)(m0>>10)*g.ldc + n)*1024 + (m0 & 1023);
        union { f16_t v[4]; uint64_t u; } pk;
        #pragma unroll
        for (int r=0;r<4;++r) pk.v[r] = (f16_t)(acc[mi][ni][r] + bv[ni]);
        *reinterpret_cast<uint64_t*>(C + idx0) = pk.u;
      }
    }
  } else {
    f32x4 bf4[4];
    #pragma unroll
    for (int ni=0; ni<4; ++ni)
      bf4[ni] = *reinterpret_cast<const f32x4*>(g.bias + bn + wc*64 + ni*16 + ((lane>>4)<<2));
    #pragma unroll
    for (int mi=0; mi<4; ++mi){
      u32 m = bm + (u32)(wr*64 + mi*16 + (lane&15));
      #pragma unroll
      for (int ni=0; ni<4; ++ni){
        u32 n0 = bn + (u32)(wc*64 + ni*16 + ((lane>>4)<<2));
        if (g.mode == 0){
          float* C = (float*)g.C;
          f32x4 v = acc[mi][ni] + bf4[ni];
          *reinterpret_cast<f32x4*>(C + (size_t)m*g.ldc + n0) = v;
        } else if (g.mode == 1){
          f16_t* C = (f16_t*)g.C;
          size_t idx = (((size_t)(m>>10)*16 + (n0>>6))*1024 + (m&1023))*64 + (n0&63);
          union { f16_t v[4]; uint64_t u; } pk;
          #pragma unroll
          for (int r=0;r<4;++r) pk.v[r] = (f16_t)(acc[mi][ni][r] + bf4[ni][r]);
          *reinterpret_cast<uint64_t*>(C + idx) = pk.u;
        } else {
          f16_t* C = (f16_t*)g.C;
          union { f16_t v[4]; uint64_t u; } pk;
          #pragma unroll
          for (int r=0;r<4;++r) pk.v[r] = (f16_t)(acc[mi][ni][r] + bf4[ni][r]);
          *reinterpret_cast<uint64_t*>(C + (size_t)m*g.ldc + n0) = pk.u;
        }
      }
    }
  }
}

// ---------------- attention pass 1: row sums of exp2 (fixed-max softmax) ----------------
// Wave owns 16 q-rows x full k-chunk. Lane: ql=lane&15 (q), h=lane>>4 (k subgroup).
template<int D, int KCH, int BSHIFT, int SCALEBIT>
__device__ __forceinline__ void pass1_body(char* smem,
    const f16_t* __restrict__ Qg, const f16_t* __restrict__ Kg,
    const float* __restrict__ mbias, float* __restrict__ statR,
    const int tid, const u32 qt, const u32 batch)
{
  constexpr int S = 1024;
  constexpr int ROWB = D*2;
  constexpr int MI = KCH/16;
  constexpr int KSL = D/32;
  char* Qs  = smem;
  char* Ks0 = smem + 128*ROWB;
  char* Ks1 = Ks0 + KCH*ROWB;

  const int lane = tid & 63, wq = tid >> 6;
  const int ql = lane & 15, h = lane >> 4;
  const float scale = SCALEBIT ? 0.1803368801111244f : 1.4426950408889634f;
  const f16_t* qb = Qg + ((size_t)batch*S + (size_t)qt*128)*D;
  const f16_t* kb = Kg + (size_t)batch*S*D;
  const float* mbb = mbias + (size_t)(batch >> BSHIFT)*S;

  stage_swz<128*ROWB, ROWB, 512>((const char*)qb, ROWB, Qs, tid);
  stage_swz<KCH*ROWB, ROWB, 512>((const char*)kb, ROWB, Ks0, tid);
  __syncthreads();

  float sacc = 0.0f;
  constexpr int NCH = S / KCH;
  for (int ch = 0; ch < NCH; ++ch){
    if (ch + 1 < NCH)
      stage_swz<KCH*ROWB, ROWB, 512>((const char*)(kb + (size_t)(ch+1)*KCH*D), ROWB, ((ch+1)&1)?Ks1:Ks0, tid);
    const char* ks = (ch&1) ? Ks1 : Ks0;

    f32x4 acc[MI] = {};
    #pragma unroll
    for (int ksl=0; ksl<KSL; ++ksl){
      f16x8 bf = frag_ld<ROWB>(Qs, (u32)(wq*16 + ql), (u32)(ksl*64 + h*16));
      #pragma unroll
      for (int mi=0; mi<MI; ++mi){
        f16x8 af = frag_ld<ROWB>(ks, (u32)(mi*16 + ql), (u32)(ksl*64 + h*16));
        acc[mi] = mfma16(af, bf, acc[mi]);
      }
    }
    #pragma unroll
    for (int mi=0; mi<MI; ++mi){
      f32x4 mb = *reinterpret_cast<const f32x4*>(mbb + ch*KCH + mi*16 + h*4);
      #pragma unroll
      for (int r=0;r<4;++r) sacc += fexp2(acc[mi][r]*scale + mb[r]);
    }
    __syncthreads();
  }

  sacc += __shfl_xor(sacc, 16);
  sacc += __shfl_xor(sacc, 32);
  if (lane < 16)
    statR[(size_t)batch*S + (size_t)qt*128 + (size_t)(wq*16) + (u32)ql] = 1.0f / sacc;
}

// ---------------- attention pass 2: direct softmax store + in-register PV ----------------
template<int D, int KCH, int BSHIFT, int SCALEBIT>
__device__ __forceinline__ void pass2_body(char* smem,
    const f16_t* __restrict__ Qg, const f16_t* __restrict__ Kg, const f16_t* __restrict__ Vtg,
    const float* __restrict__ mbias, const float* __restrict__ statR,
    float* __restrict__ attnOut, f16_t* __restrict__ xout, u32 xld, u32 xcolAdd,
    const int tid, const u32 qt, const u32 batch)
{
  constexpr int S = 1024;
  constexpr int ROWB  = D*2;
  constexpr int ROWBV = KCH*2;
  constexpr int MI   = KCH/16;   // k-token 16-blocks in chunk (= attn stores/chunk)
  constexpr int KSL  = D/32;     // QK contraction slices
  constexpr int PSL  = KCH/32;   // PV contraction slices
  constexpr int MIPV = D/16;     // d 16-blocks
  char* Qs  = smem;
  char* Ks0 = Qs + 128*ROWB;
  char* Ks1 = Ks0 + KCH*ROWB;
  char* Vs0 = Ks1 + KCH*ROWB;
  char* Vs1 = Vs0 + D*ROWBV;

  const int lane = tid & 63, wq = tid >> 6;
  const int ql = lane & 15, h = lane >> 4;
  const u32 bb = batch >> BSHIFT;
  const float scale = SCALEBIT ? 0.1803368801111244f : 1.4426950408889634f;
  const f16_t* qb = Qg + ((size_t)batch*S + (size_t)qt*128)*D;
  const f16_t* kb = Kg + (size_t)batch*S*D;
  const char* vtb = (const char*)(Vtg + (size_t)batch*D*S);
  const float* mbb = mbias + (size_t)bb*S;

  const u32 q = qt*128u + (u32)(wq*16 + ql);
  const float rreg = statR[(size_t)batch*S + q];
  float* arow = attnOut + (size_t)batch*S*S + (size_t)q*S;
  f32x4 accX[MIPV] = {};

  stage_swz<128*ROWB, ROWB, 512>((const char*)qb, ROWB, Qs, tid);
  stage_swz<KCH*ROWB, ROWB, 512>((const char*)kb, ROWB, Ks0, tid);
  stage_swz<D*ROWBV, ROWBV, 512>(vtb, (u32)(S*2), Vs0, tid);
  __syncthreads();

  // bpermute base index (bytes): src lane = ql + 16*((2h + b)&3), b from s>>1
  const int bidx = ((ql | ((h & 1) << 5)) << 2);

  constexpr int NCH = S / KCH;
  for (int ch = 0; ch < NCH; ++ch){
    // staging loads FIRST (oldest vmcnt events), stores come after
    if (ch + 1 < NCH){
      stage_swz<KCH*ROWB, ROWB, 512>((const char*)(kb + (size_t)(ch+1)*KCH*D), ROWB, ((ch+1)&1)?Ks1:Ks0, tid);
      stage_swz<D*ROWBV, ROWBV, 512>(vtb + (size_t)(ch+1)*KCH*2, (u32)(S*2), ((ch+1)&1)?Vs1:Vs0, tid);
    }
    const char* ks = (ch&1) ? Ks1 : Ks0;
    const char* vs = (ch&1) ? Vs1 : Vs0;

    // QK^T: C[k-token][q], lane holds k = mi*16 + 4h + r for its fixed q
    f32x4 acc[MI] = {};
    #pragma unroll
    for (int ksl=0; ksl<KSL; ++ksl){
      f16x8 bf = frag_ld<ROWB>(Qs, (u32)(wq*16 + ql), (u32)(ksl*64 + h*16));
      #pragma unroll
      for (int mi=0; mi<MI; ++mi){
        f16x8 af = frag_ld<ROWB>(ks, (u32)(mi*16 + ql), (u32)(ksl*64 + h*16));
        acc[mi] = mfma16(af, bf, acc[mi]);
      }
    }

    // softmax -> direct global store (plain, L2 write-back) + pack to f16 pairs
    u32 pk[MI][2];
    #pragma unroll
    for (int mi=0; mi<MI; ++mi){
      f32x4 mb = *reinterpret_cast<const f32x4*>(mbb + ch*KCH + mi*16 + h*4);
      f32x4 pv;
      #pragma unroll
      for (int r=0;r<4;++r)
        pv[r] = fexp2(acc[mi][r]*scale + mb[r]) * rreg;
      *reinterpret_cast<f32x4*>(arow + ch*KCH + mi*16 + h*4) = pv;
      pk[mi][0] = pkrtz(pv[0], pv[1]);
      pk[mi][1] = pkrtz(pv[2], pv[3]);
    }

    // PV: build B-frag (rows=q, k = psl*32 + 8h + j) via 2x bpermute + select
    #pragma unroll
    for (int psl=0; psl<PSL; ++psl){
      union { u32 w[4]; f16x8 v; } pb;
      #pragma unroll
      for (int s=0; s<4; ++s){
        int ii = bidx + ((s & 2) ? 64 : 0);
        u32 pa  = (u32)__builtin_amdgcn_ds_bpermute(ii, (int)pk[2*psl][s&1]);
        u32 pbv = (u32)__builtin_amdgcn_ds_bpermute(ii, (int)pk[2*psl+1][s&1]);
        pb.w[s] = (lane & 32) ? pbv : pa;
      }
      #pragma unroll
      for (int mi2=0; mi2<MIPV; ++mi2){
        f16x8 vf = frag_ld<ROWBV>(vs, (u32)(mi2*16 + ql), (u32)(psl*64 + h*16));
        accX[mi2] = mfma16(vf, pb.v, accX[mi2]);
      }
    }

    // drain the 2 staging loads, leave the MI attention stores in flight
    barrier_vmleave<MI>();
  }

  // write x^T to concat buffer: accX[mi2][r] = x[d = mi2*16+4h+r][q]
  u32 col0 = (batch & ((1u<<BSHIFT)-1u)) * (u32)D + xcolAdd;
  #pragma unroll
  for (int mi2=0; mi2<MIPV; ++mi2){
    union { f16_t v[4]; uint64_t u; } pk4;
    #pragma unroll
    for (int r=0;r<4;++r) pk4.v[r] = (f16_t)accX[mi2][r];
    *reinterpret_cast<uint64_t*>(xout + ((size_t)bb*S + q)*xld + col0 + mi2*16 + h*4) = pk4.u;
  }
}

// ---------------- combined attention kernels ----------------
// XCD-aware remap: blockIdx.x (=XCD via %8 round-robin) owns 17 whole heads;
// all 8 q-tiles of one head land on the SAME XCD -> K/V L2-resident.
__global__ __launch_bounds__(512, 4)
void attn_pass1_all(const f16_t* __restrict__ Qh, const f16_t* __restrict__ Kh,
                    const float* __restrict__ mbias, float* __restrict__ stRm,
                    const f16_t* __restrict__ xrf, const f16_t* __restrict__ strK,
                    const float* __restrict__ rbias, float* __restrict__ stRr)
{
  __shared__ char smem[49152];
  const int tid = threadIdx.x;
  const u32 qt = blockIdx.y & 7u;
  const u32 bh = blockIdx.x * 17u + (blockIdx.y >> 3);
  if (bh < 8u) pass1_body<128,32,0,0>(smem, xrf, strK, rbias, stRr, tid, qt, bh);
  else         pass1_body<64, 64,4,1>(smem, Qh,  Kh,   mbias, stRm, tid, qt, bh-8u);
}

__global__ __launch_bounds__(512, 4)
void attn_pass2_all(const f16_t* __restrict__ Qh, const f16_t* __restrict__ Kh,
                    const f16_t* __restrict__ Vth, const float* __restrict__ mbias,
                    const float* __restrict__ stRm, float* __restrict__ attnp,
                    const f16_t* __restrict__ xrf, const f16_t* __restrict__ strK,
                    const f16_t* __restrict__ strVt, const float* __restrict__ rbias,
                    const float* __restrict__ stRr, float* __restrict__ rsap,
                    f16_t* __restrict__ conc)
{
  __shared__ char smem[65536];
  const int tid = threadIdx.x;
  const u32 qt = blockIdx.y & 7u;
  const u32 bh = blockIdx.x * 17u + (blockIdx.y >> 3);
  if (bh < 8u) pass2_body<128,32,0,0>(smem, xrf, strK, strVt, rbias, stRr, rsap, conc, 1152u, 1024u, tid, qt, bh);
  else         pass2_body<64, 64,4,1>(smem, Qh,  Kh,   Vth,   mbias, stRm, attnp, conc, 1152u, 0u,    tid, qt, bh-8u);
}

// ---------------- launch ----------------
extern "C" void kernel_launch(void* const* d_in, const int* in_sizes, int n_in,
                              void* d_out, int out_size, void* d_ws, size_t ws_size,
                              hipStream_t stream)
{
  const float* query = (const float*)d_in[0];
  const float* key   = (const float*)d_in[1];
  const float* value = (const float*)d_in[2];
  const float* x_rsa = (const float*)d_in[3];
  const int*   mask  = (const int*)d_in[4];
  const int*   rmask = (const int*)d_in[5];
  const float* Wq = (const float*)d_in[6];  const float* bq = (const float*)d_in[7];
  const float* Wk = (const float*)d_in[8];  const float* bk = (const float*)d_in[9];
  const float* Wv = (const float*)d_in[10]; const float* bv = (const float*)d_in[11];
  const float* Wsk= (const float*)d_in[12]; const float* bsk= (const float*)d_in[13];
  const float* Wsv= (const float*)d_in[14]; const float* bsv= (const float*)d_in[15];
  const float* Wo = (const float*)d_in[16]; const float* bo = (const float*)d_in[17];

  char* ws = (char*)d_ws;
  size_t off = 0;
  auto alloc = [&](size_t bytes)->char*{ char* p = ws + off; off += (bytes + 255) & ~(size_t)255; return p; };

  f16_t* q16  = (f16_t*)alloc(16777216);
  f16_t* k16  = (f16_t*)alloc(16777216);
  f16_t* v16  = (f16_t*)alloc(16777216);
  f16_t* xrf  = (f16_t*)alloc(2097152);
  f16_t* wqT  = (f16_t*)alloc(2097152);
  f16_t* wkT  = (f16_t*)alloc(2097152);
  f16_t* wvT  = (f16_t*)alloc(2097152);
  f16_t* wskT = (f16_t*)alloc(262144);
  f16_t* wsvT = (f16_t*)alloc(262144);
  f16_t* woT  = (f16_t*)alloc(2359296);
  f16_t* Qh   = (f16_t*)alloc(16777216);
  f16_t* Kh   = (f16_t*)alloc(16777216);
  f16_t* Vth  = (f16_t*)alloc(16777216);
  f16_t* strK = (f16_t*)alloc(2097152);
  f16_t* strVt= (f16_t*)alloc(2097152);
  f16_t* conc = (f16_t*)alloc(18874368);
  float* stRm = (float*)alloc(524288);
  float* stRr = (float*)alloc(32768);
  float* mbias= (float*)alloc(32768);
  float* rbias= (float*)alloc(32768);

  // prep: converts + mask biases + weight transposes, one launch
  prep_all<<<17312,256,0,stream>>>(query, key, value, x_rsa, mask, rmask,
                                   q16, k16, v16, xrf, mbias, rbias,
                                   Wq, Wk, Wv, Wsk, Wsv, Wo,
                                   wqT, wkT, wvT, wskT, wsvT, woT);

  // all input projections in one launch: z=0 -> str (bx 0/1), z=1..3 -> Q/K/V
  {
    GPack pm{};
    pm.g[0] = {q16, wqT,  bq,  (void*)Qh,    1024u,1024u,0u,   1024u, 1};
    pm.g[1] = {k16, wkT,  bk,  (void*)Kh,    1024u,1024u,0u,   1024u, 1};
    pm.g[2] = {v16, wvT,  bv,  (void*)Vth,   1024u,1024u,1024u,1024u, 2};
    pm.g[3] = {k16, wskT, bsk, (void*)strK,  1024u,1024u,128u, 1024u, 3};
    pm.g[4] = {v16, wsvT, bsv, (void*)strVt, 1024u,1024u,128u, 1024u, 2};
    pm.single = -1;
    gemm_bt<<<dim3(8,64,4),256,0,stream>>>(pm);
  }

  float* outp  = (float*)d_out;
  float* attnp = outp + 8388608;
  float* rsap  = outp + 8388608 + 134217728;

  // attention stats
  attn_pass1_all<<<dim3(8,136),512,0,stream>>>(Qh, Kh, mbias, stRm, xrf, strK, rbias, stRr);

  // attention pass2 (softmax direct store + in-register PV into concat)
  attn_pass2_all<<<dim3(8,136),512,0,stream>>>(Qh, Kh, Vth, mbias, stRm, attnp,
                                               xrf, strK, strVt, rbias, stRr, rsap, conc);

  // output projection
  {
    GPack po{};
    po.g[0] = {conc, woT, bo, (void*)outp, 1152u,1152u,1024u,1152u, 0};
    po.g[1] = po.g[0]; po.g[2] = po.g[0]; po.g[3] = po.g[0]; po.g[4] = po.g[0];
    po.single = 0;
    gemm_bt<<<dim3(8,64,1),256,0,stream>>>(po);
  }

  (void)in_sizes; (void)n_in; (void)out_size; (void)ws_size;
}

// Round 7
// 401.924 us; speedup vs baseline: 1.0339x; 1.0139x over previous
//
#include <hip/hip_runtime.h>
#include <stdint.h>

typedef unsigned int u32;
typedef _Float16 f16_t;

typedef _Float16 f16x8 __attribute__((ext_vector_type(8)));
typedef __fp16   fp16x2 __attribute__((ext_vector_type(2)));
typedef float    f32x4 __attribute__((ext_vector_type(4)));

__device__ __forceinline__ f32x4 mfma16(f16x8 a, f16x8 b, f32x4 c){
  return __builtin_amdgcn_mfma_f32_16x16x32_f16(a, b, c, 0, 0, 0);
}
__device__ __forceinline__ float fexp2(float x){ return __builtin_amdgcn_exp2f(x); }
__device__ __forceinline__ u32 pkrtz(float a, float b){
  union { fp16x2 h; u32 u; } cv; cv.h = __builtin_amdgcn_cvt_pkrtz(a, b); return cv.u;
}

// barrier that drains staging loads but leaves the N newest VMEM ops (stores) in flight
template<int N>
__device__ __forceinline__ void barrier_vmleave(){
  asm volatile("s_waitcnt vmcnt(%0)" :: "i"(N) : "memory");
  __builtin_amdgcn_s_barrier();
}

// async global->LDS, 16B per lane; LDS dest is wave-uniform base + lane*16
__device__ __forceinline__ void gl_lds16(const void* g, void* l){
  typedef const __attribute__((address_space(1))) void* gasp;
  typedef __attribute__((address_space(3))) void* lasp;
  gasp gp = reinterpret_cast<gasp>(reinterpret_cast<uintptr_t>(g));
  lasp lp = reinterpret_cast<lasp>(static_cast<u32>(reinterpret_cast<uintptr_t>(l)));
  __builtin_amdgcn_global_load_lds(gp, lp, 16, 0, 0);
}

// Stage a [NROWS][ROWB bytes] tile: LDS[row][c'] = G[row][c' ^ sw(row)].
// Swizzle mask adapts to row size: sw = (row & (ROWB/16-1)) << 4.
template<int NBYTES, int ROWB, int NT>
__device__ __forceinline__ void stage_swz(const char* gbase, u32 gstrideB, char* lds, int tid){
  const u32 lane = (u32)(tid & 63);
  #pragma unroll
  for (int j = 0; j < NBYTES/(NT*16); ++j){
    u32 o   = (u32)(j*NT + tid) * 16u;
    u32 row = o / (u32)ROWB;
    u32 col = (o % (u32)ROWB) ^ ((row & ((u32)(ROWB>>4)-1u)) << 4);
    gl_lds16(gbase + (size_t)row * gstrideB + col, lds + (o - lane*16u));
  }
}

template<int ROWB>
__device__ __forceinline__ u32 swzb(u32 row, u32 col){
  return col ^ ((row & ((u32)(ROWB>>4)-1u)) << 4);
}

template<int ROWB>
__device__ __forceinline__ f16x8 frag_ld(const char* lds, u32 row, u32 kbyte){
  return *reinterpret_cast<const f16x8*>(lds + (size_t)row*ROWB + swzb<ROWB>(row, kbyte));
}

// ---------------- prep: converts + mask bias + weight transposes, one launch ----------------
__device__ __forceinline__ void cvt8(const float* __restrict__ in, f16_t* __restrict__ out, u32 i){
  const f32x4* p = reinterpret_cast<const f32x4*>(in) + 2*(size_t)i;
  f32x4 a = p[0], b = p[1];
  f16x8 v;
  v[0]=(f16_t)a[0]; v[1]=(f16_t)a[1]; v[2]=(f16_t)a[2]; v[3]=(f16_t)a[3];
  v[4]=(f16_t)b[0]; v[5]=(f16_t)b[1]; v[6]=(f16_t)b[2]; v[7]=(f16_t)b[3];
  *(reinterpret_cast<f16x8*>(out) + i) = v;
}

__global__ void prep_all(const float* __restrict__ q, const float* __restrict__ k,
                         const float* __restrict__ v, const float* __restrict__ xr,
                         const int* __restrict__ mask, const int* __restrict__ rmask,
                         f16_t* __restrict__ qo, f16_t* __restrict__ ko,
                         f16_t* __restrict__ vo, f16_t* __restrict__ xo,
                         float* __restrict__ mb, float* __restrict__ rb,
                         const float* __restrict__ Wq, const float* __restrict__ Wk,
                         const float* __restrict__ Wv, const float* __restrict__ Wsk,
                         const float* __restrict__ Wsv, const float* __restrict__ Wo,
                         f16_t* __restrict__ wqT, f16_t* __restrict__ wkT, f16_t* __restrict__ wvT,
                         f16_t* __restrict__ wskT, f16_t* __restrict__ wsvT, f16_t* __restrict__ woT)
{
  __shared__ float tile[32][33];
  u32 b = blockIdx.x;
  if (b < 12288u){
    const float* in; f16_t* out; u32 base;
    if (b < 4096u){ in=q; out=qo; base=0u; }
    else if (b < 8192u){ in=k; out=ko; base=4096u; }
    else { in=v; out=vo; base=8192u; }
    cvt8(in, out, (b-base)*256u + threadIdx.x);
  } else if (b < 12800u){
    cvt8(xr, xo, (b-12288u)*256u + threadIdx.x);
  } else if (b < 12832u){
    u32 i = (b-12800u)*256u + threadIdx.x;
    int m = mask[i]; int r = rmask[i];
    mb[i] = m ? 0.0f : -1.0e9f;          // log2-domain bias: exp2(-1e9)=0
    rb[i] = (m && r) ? 0.0f : -1.0e9f;
  } else {
    u32 t = b - 12832u;
    const float* W; f16_t* WT; u32 K, N, i, j;
    if (t < 3072u){
      u32 w = t >> 10, l = t & 1023u;
      W = w==0 ? Wq : w==1 ? Wk : Wv;
      WT = w==0 ? wqT : w==1 ? wkT : wvT;
      K = 1024u; N = 1024u; i = l & 31u; j = l >> 5;
    } else if (t < 3328u){
      u32 l = t - 3072u;
      W  = l < 128u ? Wsk : Wsv;
      WT = l < 128u ? wskT : wsvT;
      l &= 127u;
      K = 1024u; N = 128u; i = l & 31u; j = l >> 5;
    } else {
      u32 l = t - 3328u;
      W = Wo; WT = woT; K = 1152u; N = 1024u; i = l % 36u; j = l / 36u;
    }
    const u32 k0 = i*32u, n0 = j*32u;
    const int tt = threadIdx.x;
    const int r = tt >> 3, c4 = (tt & 7) * 4;
    f32x4 val = *reinterpret_cast<const f32x4*>(W + (size_t)(k0 + r)*N + n0 + c4);
    tile[r][c4+0]=val[0]; tile[r][c4+1]=val[1]; tile[r][c4+2]=val[2]; tile[r][c4+3]=val[3];
    __syncthreads();
    union { f16_t x[4]; uint64_t u; } pk;
    #pragma unroll
    for (int jj=0;jj<4;++jj) pk.x[jj] = (f16_t)tile[c4+jj][r];
    *reinterpret_cast<uint64_t*>(WT + (size_t)(n0 + r)*K + k0 + c4) = pk.u;
  }
}

// ---------------- GEMM: C = A * B^T (+bias) ----------------
// mode 0: f32 out plain (swapped). mode 1: f16 head layout (swapped).
// mode 2: f16 VT layout ((m>>10)*ldc+n)*1024+(m&1023), pack along m (unswapped).
// mode 3: f16 plain (swapped).
struct GArg { const f16_t* A; const f16_t* Bt; const float* bias; void* C; u32 lda, ldb, ldc, K; int mode; };
struct GPack { GArg g[5]; int single; };

__global__ __launch_bounds__(256, 2)
void gemm_bt(GPack p)
{
  __shared__ char As[2][16384];
  __shared__ char Bs[2][16384];
  GArg g; u32 bn;
  const u32 bm = blockIdx.y * 128u;
  if (p.single >= 0){ g = p.g[p.single]; bn = blockIdx.x*128u; }
  else if (blockIdx.z == 0u){ if (blockIdx.x >= 2u) return; g = p.g[3u+blockIdx.x]; bn = 0u; }
  else { g = p.g[blockIdx.z-1u]; bn = blockIdx.x*128u; }

  const int tid = threadIdx.x, lane = tid & 63, wid = tid >> 6;
  const int wr = wid >> 1, wc = wid & 1;
  const char* Ab = (const char*)(g.A + (size_t)bm * g.lda);
  const char* Bb = (const char*)(g.Bt + (size_t)bn * g.ldb);
  const u32 ldaB = g.lda*2u, ldbB = g.ldb*2u;
  const bool swp = (g.mode != 2);

  f32x4 acc[4][4] = {};
  const int nt = (int)(g.K >> 6);

  stage_swz<16384,128,256>(Ab, ldaB, As[0], tid);
  stage_swz<16384,128,256>(Bb, ldbB, Bs[0], tid);
  __syncthreads();

  for (int t = 0; t < nt; ++t){
    if (t + 1 < nt){
      stage_swz<16384,128,256>(Ab + (size_t)(t+1)*128, ldaB, As[(t+1)&1], tid);
      stage_swz<16384,128,256>(Bb + (size_t)(t+1)*128, ldbB, Bs[(t+1)&1], tid);
    }
    const char* as = As[t&1]; const char* bs = Bs[t&1];
    f16x8 af[4][2], bf[4][2];
    #pragma unroll
    for (int mi=0; mi<4; ++mi)
      #pragma unroll
      for (int ks=0; ks<2; ++ks)
        af[mi][ks] = frag_ld<128>(as, (u32)(wr*64 + mi*16 + (lane&15)), (u32)(ks*64 + ((lane>>4)<<4)));
    #pragma unroll
    for (int ni=0; ni<4; ++ni)
      #pragma unroll
      for (int ks=0; ks<2; ++ks)
        bf[ni][ks] = frag_ld<128>(bs, (u32)(wc*64 + ni*16 + (lane&15)), (u32)(ks*64 + ((lane>>4)<<4)));
    if (swp){
      #pragma unroll
      for (int mi=0; mi<4; ++mi)
        #pragma unroll
        for (int ni=0; ni<4; ++ni)
          #pragma unroll
          for (int ks=0; ks<2; ++ks)
            acc[mi][ni] = mfma16(bf[ni][ks], af[mi][ks], acc[mi][ni]);
    } else {
      #pragma unroll
      for (int mi=0; mi<4; ++mi)
        #pragma unroll
        for (int ni=0; ni<4; ++ni)
          #pragma unroll
          for (int ks=0; ks<2; ++ks)
            acc[mi][ni] = mfma16(af[mi][ks], bf[ni][ks], acc[mi][ni]);
    }
    __syncthreads();
  }

  if (g.mode == 2){
    float bv[4];
    #pragma unroll
    for (int ni=0; ni<4; ++ni) bv[ni] = g.bias[bn + wc*64 + ni*16 + (lane&15)];
    f16_t* C = (f16_t*)g.C;
    #pragma unroll
    for (int mi=0; mi<4; ++mi){
      #pragma unroll
      for (int ni=0; ni<4; ++ni){
        u32 n  = bn + (u32)(wc*64 + ni*16 + (lane&15));
        u32 m0 = bm + (u32)(wr*64 + mi*16 + ((lane>>4)<<2));
        size_t idx0 = ((size_t)(m0>>10)*g.ldc + n)*1024 + (m0 & 1023);
        union { f16_t v[4]; uint64_t u; } pk;
        #pragma unroll
        for (int r=0;r<4;++r) pk.v[r] = (f16_t)(acc[mi][ni][r] + bv[ni]);
        *reinterpret_cast<uint64_t*>(C + idx0) = pk.u;
      }
    }
  } else {
    f32x4 bf4[4];
    #pragma unroll
    for (int ni=0; ni<4; ++ni)
      bf4[ni] = *reinterpret_cast<const f32x4*>(g.bias + bn + wc*64 + ni*16 + ((lane>>4)<<2));
    #pragma unroll
    for (int mi=0; mi<4; ++mi){
      u32 m = bm + (u32)(wr*64 + mi*16 + (lane&15));
      #pragma unroll
      for (int ni=0; ni<4; ++ni){
        u32 n0 = bn + (u32)(wc*64 + ni*16 + ((lane>>4)<<2));
        if (g.mode == 0){
          float* C = (float*)g.C;
          f32x4 v = acc[mi][ni] + bf4[ni];
          *reinterpret_cast<f32x4*>(C + (size_t)m*g.ldc + n0) = v;
        } else if (g.mode == 1){
          f16_t* C = (f16_t*)g.C;
          size_t idx = (((size_t)(m>>10)*16 + (n0>>6))*1024 + (m&1023))*64 + (n0&63);
          union { f16_t v[4]; uint64_t u; } pk;
          #pragma unroll
          for (int r=0;r<4;++r) pk.v[r] = (f16_t)(acc[mi][ni][r] + bf4[ni][r]);
          *reinterpret_cast<uint64_t*>(C + idx) = pk.u;
        } else {
          f16_t* C = (f16_t*)g.C;
          union { f16_t v[4]; uint64_t u; } pk;
          #pragma unroll
          for (int r=0;r<4;++r) pk.v[r] = (f16_t)(acc[mi][ni][r] + bf4[ni][r]);
          *reinterpret_cast<uint64_t*>(C + (size_t)m*g.ldc + n0) = pk.u;
        }
      }
    }
  }
}

// ---------------- fused attention: loop1 row-sums, loop2 softmax store + PV ----------------
// Wave owns 16 q-rows x full k-chunk. Lane: ql=lane&15 (q), h=lane>>4 (k subgroup).
template<int D, int KCH, int BSHIFT, int SCALEBIT>
__device__ __forceinline__ void attn_fused_body(char* smem,
    const f16_t* __restrict__ Qg, const f16_t* __restrict__ Kg, const f16_t* __restrict__ Vtg,
    const float* __restrict__ mbias,
    float* __restrict__ attnOut, f16_t* __restrict__ xout, u32 xld, u32 xcolAdd,
    const int tid, const u32 qt, const u32 batch)
{
  constexpr int S = 1024;
  constexpr int ROWB  = D*2;
  constexpr int ROWBV = KCH*2;
  constexpr int MI   = KCH/16;   // k-token 16-blocks in chunk (= attn stores/chunk)
  constexpr int KSL  = D/32;     // QK contraction slices
  constexpr int PSL  = KCH/32;   // PV contraction slices
  constexpr int MIPV = D/16;     // d 16-blocks
  char* Qs  = smem;
  char* Ks0 = Qs + 128*ROWB;
  char* Ks1 = Ks0 + KCH*ROWB;
  char* Vs0 = Ks1 + KCH*ROWB;
  char* Vs1 = Vs0 + D*ROWBV;

  const int lane = tid & 63, wq = tid >> 6;
  const int ql = lane & 15, h = lane >> 4;
  const u32 bb = batch >> BSHIFT;
  const float scale = SCALEBIT ? 0.1803368801111244f : 1.4426950408889634f;
  const f16_t* qb = Qg + ((size_t)batch*S + (size_t)qt*128)*D;
  const f16_t* kb = Kg + (size_t)batch*S*D;
  const char* vtb = (const char*)(Vtg + (size_t)batch*D*S);
  const float* mbb = mbias + (size_t)bb*S;

  const u32 q = qt*128u + (u32)(wq*16 + ql);
  float* arow = attnOut + (size_t)batch*S*S + (size_t)q*S;

  constexpr int NCH = S / KCH;

  // ---- loop 1: row sums of exp2 (K only) ----
  stage_swz<128*ROWB, ROWB, 512>((const char*)qb, ROWB, Qs, tid);
  stage_swz<KCH*ROWB, ROWB, 512>((const char*)kb, ROWB, Ks0, tid);
  __syncthreads();

  float sacc = 0.0f;
  for (int ch = 0; ch < NCH; ++ch){
    if (ch + 1 < NCH)
      stage_swz<KCH*ROWB, ROWB, 512>((const char*)(kb + (size_t)(ch+1)*KCH*D), ROWB, ((ch+1)&1)?Ks1:Ks0, tid);
    const char* ks = (ch&1) ? Ks1 : Ks0;

    f32x4 acc[MI] = {};
    #pragma unroll
    for (int ksl=0; ksl<KSL; ++ksl){
      f16x8 bf = frag_ld<ROWB>(Qs, (u32)(wq*16 + ql), (u32)(ksl*64 + h*16));
      #pragma unroll
      for (int mi=0; mi<MI; ++mi){
        f16x8 af = frag_ld<ROWB>(ks, (u32)(mi*16 + ql), (u32)(ksl*64 + h*16));
        acc[mi] = mfma16(af, bf, acc[mi]);
      }
    }
    #pragma unroll
    for (int mi=0; mi<MI; ++mi){
      f32x4 mb = *reinterpret_cast<const f32x4*>(mbb + ch*KCH + mi*16 + h*4);
      #pragma unroll
      for (int r=0;r<4;++r) sacc += fexp2(acc[mi][r]*scale + mb[r]);
    }
    __syncthreads();
  }

  sacc += __shfl_xor(sacc, 16);
  sacc += __shfl_xor(sacc, 32);
  const float rreg = 1.0f / sacc;   // every lane now holds its q-row's normalizer

  // ---- loop 2: softmax store + in-register PV ----
  f32x4 accX[MIPV] = {};
  stage_swz<KCH*ROWB, ROWB, 512>((const char*)kb, ROWB, Ks0, tid);
  stage_swz<D*ROWBV, ROWBV, 512>(vtb, (u32)(S*2), Vs0, tid);
  __syncthreads();

  // bpermute base index (bytes): src lane = ql + 16*((2h + b)&3), b from s>>1
  const int bidx = ((ql | ((h & 1) << 5)) << 2);

  for (int ch = 0; ch < NCH; ++ch){
    // staging loads FIRST (oldest vmcnt events), stores come after
    if (ch + 1 < NCH){
      stage_swz<KCH*ROWB, ROWB, 512>((const char*)(kb + (size_t)(ch+1)*KCH*D), ROWB, ((ch+1)&1)?Ks1:Ks0, tid);
      stage_swz<D*ROWBV, ROWBV, 512>(vtb + (size_t)(ch+1)*KCH*2, (u32)(S*2), ((ch+1)&1)?Vs1:Vs0, tid);
    }
    const char* ks = (ch&1) ? Ks1 : Ks0;
    const char* vs = (ch&1) ? Vs1 : Vs0;

    // QK^T: C[k-token][q], lane holds k = mi*16 + 4h + r for its fixed q
    f32x4 acc[MI] = {};
    #pragma unroll
    for (int ksl=0; ksl<KSL; ++ksl){
      f16x8 bf = frag_ld<ROWB>(Qs, (u32)(wq*16 + ql), (u32)(ksl*64 + h*16));
      #pragma unroll
      for (int mi=0; mi<MI; ++mi){
        f16x8 af = frag_ld<ROWB>(ks, (u32)(mi*16 + ql), (u32)(ksl*64 + h*16));
        acc[mi] = mfma16(af, bf, acc[mi]);
      }
    }

    // softmax -> direct global store (plain, L2 write-back) + pack to f16 pairs
    u32 pk[MI][2];
    #pragma unroll
    for (int mi=0; mi<MI; ++mi){
      f32x4 mb = *reinterpret_cast<const f32x4*>(mbb + ch*KCH + mi*16 + h*4);
      f32x4 pv;
      #pragma unroll
      for (int r=0;r<4;++r)
        pv[r] = fexp2(acc[mi][r]*scale + mb[r]) * rreg;
      *reinterpret_cast<f32x4*>(arow + ch*KCH + mi*16 + h*4) = pv;
      pk[mi][0] = pkrtz(pv[0], pv[1]);
      pk[mi][1] = pkrtz(pv[2], pv[3]);
    }

    // PV: build B-frag (rows=q, k = psl*32 + 8h + j) via 2x bpermute + select
    #pragma unroll
    for (int psl=0; psl<PSL; ++psl){
      union { u32 w[4]; f16x8 v; } pb;
      #pragma unroll
      for (int s=0; s<4; ++s){
        int ii = bidx + ((s & 2) ? 64 : 0);
        u32 pa  = (u32)__builtin_amdgcn_ds_bpermute(ii, (int)pk[2*psl][s&1]);
        u32 pbv = (u32)__builtin_amdgcn_ds_bpermute(ii, (int)pk[2*psl+1][s&1]);
        pb.w[s] = (lane & 32) ? pbv : pa;
      }
      #pragma unroll
      for (int mi2=0; mi2<MIPV; ++mi2){
        f16x8 vf = frag_ld<ROWBV>(vs, (u32)(mi2*16 + ql), (u32)(psl*64 + h*16));
        accX[mi2] = mfma16(vf, pb.v, accX[mi2]);
      }
    }

    // drain the 2 staging loads, leave the MI attention stores in flight
    barrier_vmleave<MI>();
  }

  // write x^T to concat buffer: accX[mi2][r] = x[d = mi2*16+4h+r][q]
  u32 col0 = (batch & ((1u<<BSHIFT)-1u)) * (u32)D + xcolAdd;
  #pragma unroll
  for (int mi2=0; mi2<MIPV; ++mi2){
    union { f16_t v[4]; uint64_t u; } pk4;
    #pragma unroll
    for (int r=0;r<4;++r) pk4.v[r] = (f16_t)accX[mi2][r];
    *reinterpret_cast<uint64_t*>(xout + ((size_t)bb*S + q)*xld + col0 + mi2*16 + h*4) = pk4.u;
  }
}

// ---------------- combined attention kernel ----------------
// XCD-aware remap: blockIdx.x (=XCD via %8 round-robin) owns 17 whole heads;
// all 8 q-tiles of one head land on the SAME XCD -> K/V L2-resident.
__global__ __launch_bounds__(512, 4)
void attn_all(const f16_t* __restrict__ Qh, const f16_t* __restrict__ Kh,
              const f16_t* __restrict__ Vth, const float* __restrict__ mbias,
              float* __restrict__ attnp,
              const f16_t* __restrict__ xrf, const f16_t* __restrict__ strK,
              const f16_t* __restrict__ strVt, const float* __restrict__ rbias,
              float* __restrict__ rsap,
              f16_t* __restrict__ conc)
{
  __shared__ char smem[65536];
  const int tid = threadIdx.x;
  const u32 qt = blockIdx.y & 7u;
  const u32 bh = blockIdx.x * 17u + (blockIdx.y >> 3);
  if (bh < 8u) attn_fused_body<128,32,0,0>(smem, xrf, strK, strVt, rbias, rsap, conc, 1152u, 1024u, tid, qt, bh);
  else         attn_fused_body<64, 64,4,1>(smem, Qh,  Kh,   Vth,   mbias, attnp, conc, 1152u, 0u,    tid, qt, bh-8u);
}

// ---------------- launch ----------------
extern "C" void kernel_launch(void* const* d_in, const int* in_sizes, int n_in,
                              void* d_out, int out_size, void* d_ws, size_t ws_size,
                              hipStream_t stream)
{
  const float* query = (const float*)d_in[0];
  const float* key   = (const float*)d_in[1];
  const float* value = (const float*)d_in[2];
  const float* x_rsa = (const float*)d_in[3];
  const int*   mask  = (const int*)d_in[4];
  const int*   rmask = (const int*)d_in[5];
  const float* Wq = (const float*)d_in[6];  const float* bq = (const float*)d_in[7];
  const float* Wk = (const float*)d_in[8];  const float* bk = (const float*)d_in[9];
  const float* Wv = (const float*)d_in[10]; const float* bv = (const float*)d_in[11];
  const float* Wsk= (const float*)d_in[12]; const float* bsk= (const float*)d_in[13];
  const float* Wsv= (const float*)d_in[14]; const float* bsv= (const float*)d_in[15];
  const float* Wo = (const float*)d_in[16]; const float* bo = (const float*)d_in[17];

  char* ws = (char*)d_ws;
  size_t off = 0;
  auto alloc = [&](size_t bytes)->char*{ char* p = ws + off; off += (bytes + 255) & ~(size_t)255; return p; };

  f16_t* q16  = (f16_t*)alloc(16777216);
  f16_t* k16  = (f16_t*)alloc(16777216);
  f16_t* v16  = (f16_t*)alloc(16777216);
  f16_t* xrf  = (f16_t*)alloc(2097152);
  f16_t* wqT  = (f16_t*)alloc(2097152);
  f16_t* wkT  = (f16_t*)alloc(2097152);
  f16_t* wvT  = (f16_t*)alloc(2097152);
  f16_t* wskT = (f16_t*)alloc(262144);
  f16_t* wsvT = (f16_t*)alloc(262144);
  f16_t* woT  = (f16_t*)alloc(2359296);
  f16_t* Qh   = (f16_t*)alloc(16777216);
  f16_t* Kh   = (f16_t*)alloc(16777216);
  f16_t* Vth  = (f16_t*)alloc(16777216);
  f16_t* strK = (f16_t*)alloc(2097152);
  f16_t* strVt= (f16_t*)alloc(2097152);
  f16_t* conc = (f16_t*)alloc(18874368);
  float* mbias= (float*)alloc(32768);
  float* rbias= (float*)alloc(32768);

  // prep: converts + mask biases + weight transposes, one launch
  prep_all<<<17312,256,0,stream>>>(query, key, value, x_rsa, mask, rmask,
                                   q16, k16, v16, xrf, mbias, rbias,
                                   Wq, Wk, Wv, Wsk, Wsv, Wo,
                                   wqT, wkT, wvT, wskT, wsvT, woT);

  // all input projections in one launch: z=0 -> str (bx 0/1), z=1..3 -> Q/K/V
  {
    GPack pm{};
    pm.g[0] = {q16, wqT,  bq,  (void*)Qh,    1024u,1024u,0u,   1024u, 1};
    pm.g[1] = {k16, wkT,  bk,  (void*)Kh,    1024u,1024u,0u,   1024u, 1};
    pm.g[2] = {v16, wvT,  bv,  (void*)Vth,   1024u,1024u,1024u,1024u, 2};
    pm.g[3] = {k16, wskT, bsk, (void*)strK,  1024u,1024u,128u, 1024u, 3};
    pm.g[4] = {v16, wsvT, bsv, (void*)strVt, 1024u,1024u,128u, 1024u, 2};
    pm.single = -1;
    gemm_bt<<<dim3(8,64,4),256,0,stream>>>(pm);
  }

  float* outp  = (float*)d_out;
  float* attnp = outp + 8388608;
  float* rsap  = outp + 8388608 + 134217728;

  // fused attention (row-sums + softmax store + PV into concat), one launch
  attn_all<<<dim3(8,136),512,0,stream>>>(Qh, Kh, Vth, mbias, attnp,
                                         xrf, strK, strVt, rbias, rsap, conc);

  // output projection
  {
    GPack po{};
    po.g[0] = {conc, woT, bo, (void*)outp, 1152u,1152u,1024u,1152u, 0};
    po.g[1] = po.g[0]; po.g[2] = po.g[0]; po.g[3] = po.g[0]; po.g[4] = po.g[0];
    po.single = 0;
    gemm_bt<<<dim3(8,64,1),256,0,stream>>>(po);
  }

  (void)in_sizes; (void)n_in; (void)out_size; (void)ws_size;
}

// Round 8
// 401.039 us; speedup vs baseline: 1.0362x; 1.0022x over previous
//
#include <hip/hip_runtime.h>
#include <stdint.h>

typedef unsigned int u32;
typedef _Float16 f16_t;

typedef _Float16 f16x8 __attribute__((ext_vector_type(8)));
typedef __fp16   fp16x2 __attribute__((ext_vector_type(2)));
typedef float    f32x4 __attribute__((ext_vector_type(4)));

__device__ __forceinline__ f32x4 mfma16(f16x8 a, f16x8 b, f32x4 c){
  return __builtin_amdgcn_mfma_f32_16x16x32_f16(a, b, c, 0, 0, 0);
}
__device__ __forceinline__ float fexp2(float x){ return __builtin_amdgcn_exp2f(x); }
__device__ __forceinline__ u32 pkrtz(float a, float b){
  union { fp16x2 h; u32 u; } cv; cv.h = __builtin_amdgcn_cvt_pkrtz(a, b); return cv.u;
}

// barrier that drains staging loads but leaves the N newest VMEM ops (stores) in flight
template<int N>
__device__ __forceinline__ void barrier_vmleave(){
  asm volatile("s_waitcnt vmcnt(%0)" :: "i"(N) : "memory");
  __builtin_amdgcn_s_barrier();
}

// async global->LDS, 16B per lane; LDS dest is wave-uniform base + lane*16
__device__ __forceinline__ void gl_lds16(const void* g, void* l){
  typedef const __attribute__((address_space(1))) void* gasp;
  typedef __attribute__((address_space(3))) void* lasp;
  gasp gp = reinterpret_cast<gasp>(reinterpret_cast<uintptr_t>(g));
  lasp lp = reinterpret_cast<lasp>(static_cast<u32>(reinterpret_cast<uintptr_t>(l)));
  __builtin_amdgcn_global_load_lds(gp, lp, 16, 0, 0);
}

// Stage a [NROWS][ROWB bytes] tile: LDS[row][c'] = G[row][c' ^ sw(row)].
// Swizzle mask adapts to row size: sw = (row & (ROWB/16-1)) << 4.
template<int NBYTES, int ROWB, int NT>
__device__ __forceinline__ void stage_swz(const char* gbase, u32 gstrideB, char* lds, int tid){
  const u32 lane = (u32)(tid & 63);
  #pragma unroll
  for (int j = 0; j < NBYTES/(NT*16); ++j){
    u32 o   = (u32)(j*NT + tid) * 16u;
    u32 row = o / (u32)ROWB;
    u32 col = (o % (u32)ROWB) ^ ((row & ((u32)(ROWB>>4)-1u)) << 4);
    gl_lds16(gbase + (size_t)row * gstrideB + col, lds + (o - lane*16u));
  }
}

template<int ROWB>
__device__ __forceinline__ u32 swzb(u32 row, u32 col){
  return col ^ ((row & ((u32)(ROWB>>4)-1u)) << 4);
}

template<int ROWB>
__device__ __forceinline__ f16x8 frag_ld(const char* lds, u32 row, u32 kbyte){
  return *reinterpret_cast<const f16x8*>(lds + (size_t)row*ROWB + swzb<ROWB>(row, kbyte));
}

// ---------------- prep: converts + mask bias + weight transposes, one launch ----------------
__device__ __forceinline__ void cvt8(const float* __restrict__ in, f16_t* __restrict__ out, u32 i){
  const f32x4* p = reinterpret_cast<const f32x4*>(in) + 2*(size_t)i;
  f32x4 a = p[0], b = p[1];
  f16x8 v;
  v[0]=(f16_t)a[0]; v[1]=(f16_t)a[1]; v[2]=(f16_t)a[2]; v[3]=(f16_t)a[3];
  v[4]=(f16_t)b[0]; v[5]=(f16_t)b[1]; v[6]=(f16_t)b[2]; v[7]=(f16_t)b[3];
  *(reinterpret_cast<f16x8*>(out) + i) = v;
}

__global__ void prep_all(const float* __restrict__ q, const float* __restrict__ k,
                         const float* __restrict__ v, const float* __restrict__ xr,
                         const int* __restrict__ mask, const int* __restrict__ rmask,
                         f16_t* __restrict__ qo, f16_t* __restrict__ ko,
                         f16_t* __restrict__ vo, f16_t* __restrict__ xo,
                         float* __restrict__ mb, float* __restrict__ rb,
                         const float* __restrict__ Wq, const float* __restrict__ Wk,
                         const float* __restrict__ Wv, const float* __restrict__ Wsk,
                         const float* __restrict__ Wsv, const float* __restrict__ Wo,
                         f16_t* __restrict__ wqT, f16_t* __restrict__ wkT, f16_t* __restrict__ wvT,
                         f16_t* __restrict__ wskT, f16_t* __restrict__ wsvT, f16_t* __restrict__ woT)
{
  __shared__ float tile[32][33];
  u32 b = blockIdx.x;
  if (b < 12288u){
    const float* in; f16_t* out; u32 base;
    if (b < 4096u){ in=q; out=qo; base=0u; }
    else if (b < 8192u){ in=k; out=ko; base=4096u; }
    else { in=v; out=vo; base=8192u; }
    cvt8(in, out, (b-base)*256u + threadIdx.x);
  } else if (b < 12800u){
    cvt8(xr, xo, (b-12288u)*256u + threadIdx.x);
  } else if (b < 12832u){
    u32 i = (b-12800u)*256u + threadIdx.x;
    int m = mask[i]; int r = rmask[i];
    mb[i] = m ? 0.0f : -1.0e9f;          // log2-domain bias: exp2(-1e9)=0
    rb[i] = (m && r) ? 0.0f : -1.0e9f;
  } else {
    u32 t = b - 12832u;
    const float* W; f16_t* WT; u32 K, N, i, j;
    if (t < 3072u){
      u32 w = t >> 10, l = t & 1023u;
      W = w==0 ? Wq : w==1 ? Wk : Wv;
      WT = w==0 ? wqT : w==1 ? wkT : wvT;
      K = 1024u; N = 1024u; i = l & 31u; j = l >> 5;
    } else if (t < 3328u){
      u32 l = t - 3072u;
      W  = l < 128u ? Wsk : Wsv;
      WT = l < 128u ? wskT : wsvT;
      l &= 127u;
      K = 1024u; N = 128u; i = l & 31u; j = l >> 5;
    } else {
      u32 l = t - 3328u;
      W = Wo; WT = woT; K = 1152u; N = 1024u; i = l % 36u; j = l / 36u;
    }
    const u32 k0 = i*32u, n0 = j*32u;
    const int tt = threadIdx.x;
    const int r = tt >> 3, c4 = (tt & 7) * 4;
    f32x4 val = *reinterpret_cast<const f32x4*>(W + (size_t)(k0 + r)*N + n0 + c4);
    tile[r][c4+0]=val[0]; tile[r][c4+1]=val[1]; tile[r][c4+2]=val[2]; tile[r][c4+3]=val[3];
    __syncthreads();
    union { f16_t x[4]; uint64_t u; } pk;
    #pragma unroll
    for (int jj=0;jj<4;++jj) pk.x[jj] = (f16_t)tile[c4+jj][r];
    *reinterpret_cast<uint64_t*>(WT + (size_t)(n0 + r)*K + k0 + c4) = pk.u;
  }
}

// ---------------- GEMM: C = A * B^T (+bias) ----------------
// mode 0: f32 out plain (swapped). mode 1: f16 head layout (swapped).
// mode 2: f16 VT layout ((m>>10)*ldc+n)*1024+(m&1023), pack along m (unswapped).
// mode 3: f16 plain (swapped).
struct GArg { const f16_t* A; const f16_t* Bt; const float* bias; void* C; u32 lda, ldb, ldc, K; int mode; };
struct GPack { GArg g[5]; int single; };

__global__ __launch_bounds__(256, 2)
void gemm_bt(GPack p)
{
  __shared__ char As[2][16384];
  __shared__ char Bs[2][16384];
  GArg g; u32 bn;
  const u32 bm = blockIdx.y * 128u;
  if (p.single >= 0){ g = p.g[p.single]; bn = blockIdx.x*128u; }
  else if (blockIdx.z == 0u){ if (blockIdx.x >= 2u) return; g = p.g[3u+blockIdx.x]; bn = 0u; }
  else { g = p.g[blockIdx.z-1u]; bn = blockIdx.x*128u; }

  const int tid = threadIdx.x, lane = tid & 63, wid = tid >> 6;
  const int wr = wid >> 1, wc = wid & 1;
  const char* Ab = (const char*)(g.A + (size_t)bm * g.lda);
  const char* Bb = (const char*)(g.Bt + (size_t)bn * g.ldb);
  const u32 ldaB = g.lda*2u, ldbB = g.ldb*2u;
  const bool swp = (g.mode != 2);

  f32x4 acc[4][4] = {};
  const int nt = (int)(g.K >> 6);

  stage_swz<16384,128,256>(Ab, ldaB, As[0], tid);
  stage_swz<16384,128,256>(Bb, ldbB, Bs[0], tid);
  __syncthreads();

  for (int t = 0; t < nt; ++t){
    if (t + 1 < nt){
      stage_swz<16384,128,256>(Ab + (size_t)(t+1)*128, ldaB, As[(t+1)&1], tid);
      stage_swz<16384,128,256>(Bb + (size_t)(t+1)*128, ldbB, Bs[(t+1)&1], tid);
    }
    const char* as = As[t&1]; const char* bs = Bs[t&1];
    f16x8 af[4][2], bf[4][2];
    #pragma unroll
    for (int mi=0; mi<4; ++mi)
      #pragma unroll
      for (int ks=0; ks<2; ++ks)
        af[mi][ks] = frag_ld<128>(as, (u32)(wr*64 + mi*16 + (lane&15)), (u32)(ks*64 + ((lane>>4)<<4)));
    #pragma unroll
    for (int ni=0; ni<4; ++ni)
      #pragma unroll
      for (int ks=0; ks<2; ++ks)
        bf[ni][ks] = frag_ld<128>(bs, (u32)(wc*64 + ni*16 + (lane&15)), (u32)(ks*64 + ((lane>>4)<<4)));
    if (swp){
      #pragma unroll
      for (int mi=0; mi<4; ++mi)
        #pragma unroll
        for (int ni=0; ni<4; ++ni)
          #pragma unroll
          for (int ks=0; ks<2; ++ks)
            acc[mi][ni] = mfma16(bf[ni][ks], af[mi][ks], acc[mi][ni]);
    } else {
      #pragma unroll
      for (int mi=0; mi<4; ++mi)
        #pragma unroll
        for (int ni=0; ni<4; ++ni)
          #pragma unroll
          for (int ks=0; ks<2; ++ks)
            acc[mi][ni] = mfma16(af[mi][ks], bf[ni][ks], acc[mi][ni]);
    }
    __syncthreads();
  }

  if (g.mode == 2){
    float bv[4];
    #pragma unroll
    for (int ni=0; ni<4; ++ni) bv[ni] = g.bias[bn + wc*64 + ni*16 + (lane&15)];
    f16_t* C = (f16_t*)g.C;
    #pragma unroll
    for (int mi=0; mi<4; ++mi){
      #pragma unroll
      for (int ni=0; ni<4; ++ni){
        u32 n  = bn + (u32)(wc*64 + ni*16 + (lane&15));
        u32 m0 = bm + (u32)(wr*64 + mi*16 + ((lane>>4)<<2));
        size_t idx0 = ((size_t)(m0>>10)*g.ldc + n)*1024 + (m0 & 1023);
        union { f16_t v[4]; uint64_t u; } pk;
        #pragma unroll
        for (int r=0;r<4;++r) pk.v[r] = (f16_t)(acc[mi][ni][r] + bv[ni]);
        *reinterpret_cast<uint64_t*>(C + idx0) = pk.u;
      }
    }
  } else {
    f32x4 bf4[4];
    #pragma unroll
    for (int ni=0; ni<4; ++ni)
      bf4[ni] = *reinterpret_cast<const f32x4*>(g.bias + bn + wc*64 + ni*16 + ((lane>>4)<<2));
    #pragma unroll
    for (int mi=0; mi<4; ++mi){
      u32 m = bm + (u32)(wr*64 + mi*16 + (lane&15));
      #pragma unroll
      for (int ni=0; ni<4; ++ni){
        u32 n0 = bn + (u32)(wc*64 + ni*16 + ((lane>>4)<<2));
        if (g.mode == 0){
          float* C = (float*)g.C;
          f32x4 v = acc[mi][ni] + bf4[ni];
          *reinterpret_cast<f32x4*>(C + (size_t)m*g.ldc + n0) = v;
        } else if (g.mode == 1){
          f16_t* C = (f16_t*)g.C;
          size_t idx = (((size_t)(m>>10)*16 + (n0>>6))*1024 + (m&1023))*64 + (n0&63);
          union { f16_t v[4]; uint64_t u; } pk;
          #pragma unroll
          for (int r=0;r<4;++r) pk.v[r] = (f16_t)(acc[mi][ni][r] + bf4[ni][r]);
          *reinterpret_cast<uint64_t*>(C + idx) = pk.u;
        } else {
          f16_t* C = (f16_t*)g.C;
          union { f16_t v[4]; uint64_t u; } pk;
          #pragma unroll
          for (int r=0;r<4;++r) pk.v[r] = (f16_t)(acc[mi][ni][r] + bf4[ni][r]);
          *reinterpret_cast<uint64_t*>(C + (size_t)m*g.ldc + n0) = pk.u;
        }
      }
    }
  }
}

// ---------------- fused attention: loop1 row-sums, loop2 softmax store + PV ----------------
// Wave owns 16 q-rows x full k-chunk. Lane: ql=lane&15 (q), h=lane>>4 (k subgroup).
template<int D, int KCH, int BSHIFT, int SCALEBIT>
__device__ __forceinline__ void attn_fused_body(char* smem,
    const f16_t* __restrict__ Qg, const f16_t* __restrict__ Kg, const f16_t* __restrict__ Vtg,
    const float* __restrict__ mbias,
    float* __restrict__ attnOut, f16_t* __restrict__ xout, u32 xld, u32 xcolAdd,
    const int tid, const u32 qt, const u32 batch)
{
  constexpr int S = 1024;
  constexpr int ROWB  = D*2;
  constexpr int ROWBV = KCH*2;
  constexpr int MI   = KCH/16;   // k-token 16-blocks in chunk (= attn stores/chunk)
  constexpr int KSL  = D/32;     // QK contraction slices
  constexpr int PSL  = KCH/32;   // PV contraction slices
  constexpr int MIPV = D/16;     // d 16-blocks
  char* Qs  = smem;
  char* Ks0 = Qs + 128*ROWB;
  char* Ks1 = Ks0 + KCH*ROWB;
  char* Vs0 = Ks1 + KCH*ROWB;
  char* Vs1 = Vs0 + D*ROWBV;

  const int lane = tid & 63, wq = tid >> 6;
  const int ql = lane & 15, h = lane >> 4;
  const u32 bb = batch >> BSHIFT;
  const float scale = SCALEBIT ? 0.1803368801111244f : 1.4426950408889634f;
  const f16_t* qb = Qg + ((size_t)batch*S + (size_t)qt*128)*D;
  const f16_t* kb = Kg + (size_t)batch*S*D;
  const char* vtb = (const char*)(Vtg + (size_t)batch*D*S);
  const float* mbb = mbias + (size_t)bb*S;

  const u32 q = qt*128u + (u32)(wq*16 + ql);
  float* arow = attnOut + (size_t)batch*S*S + (size_t)q*S;

  constexpr int NCH = S / KCH;

  // ---- loop 1: row sums of exp2 (K only) ----
  stage_swz<128*ROWB, ROWB, 512>((const char*)qb, ROWB, Qs, tid);
  stage_swz<KCH*ROWB, ROWB, 512>((const char*)kb, ROWB, Ks0, tid);
  __syncthreads();

  float sacc = 0.0f;
  for (int ch = 0; ch < NCH; ++ch){
    if (ch + 1 < NCH)
      stage_swz<KCH*ROWB, ROWB, 512>((const char*)(kb + (size_t)(ch+1)*KCH*D), ROWB, ((ch+1)&1)?Ks1:Ks0, tid);
    const char* ks = (ch&1) ? Ks1 : Ks0;

    f32x4 acc[MI] = {};
    #pragma unroll
    for (int ksl=0; ksl<KSL; ++ksl){
      f16x8 bf = frag_ld<ROWB>(Qs, (u32)(wq*16 + ql), (u32)(ksl*64 + h*16));
      #pragma unroll
      for (int mi=0; mi<MI; ++mi){
        f16x8 af = frag_ld<ROWB>(ks, (u32)(mi*16 + ql), (u32)(ksl*64 + h*16));
        acc[mi] = mfma16(af, bf, acc[mi]);
      }
    }
    #pragma unroll
    for (int mi=0; mi<MI; ++mi){
      f32x4 mb = *reinterpret_cast<const f32x4*>(mbb + ch*KCH + mi*16 + h*4);
      #pragma unroll
      for (int r=0;r<4;++r) sacc += fexp2(acc[mi][r]*scale + mb[r]);
    }
    __syncthreads();
  }

  sacc += __shfl_xor(sacc, 16);
  sacc += __shfl_xor(sacc, 32);
  const float rreg = 1.0f / sacc;   // every lane now holds its q-row's normalizer

  // ---- loop 2: softmax store + in-register PV ----
  f32x4 accX[MIPV] = {};
  stage_swz<KCH*ROWB, ROWB, 512>((const char*)kb, ROWB, Ks0, tid);
  stage_swz<D*ROWBV, ROWBV, 512>(vtb, (u32)(S*2), Vs0, tid);
  __syncthreads();

  // bpermute base index (bytes): src lane = ql + 16*((2h + b)&3), b from s>>1
  const int bidx = ((ql | ((h & 1) << 5)) << 2);

  for (int ch = 0; ch < NCH; ++ch){
    // staging loads FIRST (oldest vmcnt events), stores come after
    if (ch + 1 < NCH){
      stage_swz<KCH*ROWB, ROWB, 512>((const char*)(kb + (size_t)(ch+1)*KCH*D), ROWB, ((ch+1)&1)?Ks1:Ks0, tid);
      stage_swz<D*ROWBV, ROWBV, 512>(vtb + (size_t)(ch+1)*KCH*2, (u32)(S*2), ((ch+1)&1)?Vs1:Vs0, tid);
    }
    const char* ks = (ch&1) ? Ks1 : Ks0;
    const char* vs = (ch&1) ? Vs1 : Vs0;

    // QK^T: C[k-token][q], lane holds k = mi*16 + 4h + r for its fixed q
    f32x4 acc[MI] = {};
    #pragma unroll
    for (int ksl=0; ksl<KSL; ++ksl){
      f16x8 bf = frag_ld<ROWB>(Qs, (u32)(wq*16 + ql), (u32)(ksl*64 + h*16));
      #pragma unroll
      for (int mi=0; mi<MI; ++mi){
        f16x8 af = frag_ld<ROWB>(ks, (u32)(mi*16 + ql), (u32)(ksl*64 + h*16));
        acc[mi] = mfma16(af, bf, acc[mi]);
      }
    }

    // softmax -> direct global store (plain, L2 write-back) + pack to f16 pairs
    u32 pk[MI][2];
    #pragma unroll
    for (int mi=0; mi<MI; ++mi){
      f32x4 mb = *reinterpret_cast<const f32x4*>(mbb + ch*KCH + mi*16 + h*4);
      f32x4 pv;
      #pragma unroll
      for (int r=0;r<4;++r)
        pv[r] = fexp2(acc[mi][r]*scale + mb[r]) * rreg;
      *reinterpret_cast<f32x4*>(arow + ch*KCH + mi*16 + h*4) = pv;
      pk[mi][0] = pkrtz(pv[0], pv[1]);
      pk[mi][1] = pkrtz(pv[2], pv[3]);
    }

    // PV: build B-frag (rows=q, k = psl*32 + 8h + j) via 2x bpermute + select
    #pragma unroll
    for (int psl=0; psl<PSL; ++psl){
      union { u32 w[4]; f16x8 v; } pb;
      #pragma unroll
      for (int s=0; s<4; ++s){
        int ii = bidx + ((s & 2) ? 64 : 0);
        u32 pa  = (u32)__builtin_amdgcn_ds_bpermute(ii, (int)pk[2*psl][s&1]);
        u32 pbv = (u32)__builtin_amdgcn_ds_bpermute(ii, (int)pk[2*psl+1][s&1]);
        pb.w[s] = (lane & 32) ? pbv : pa;
      }
      #pragma unroll
      for (int mi2=0; mi2<MIPV; ++mi2){
        f16x8 vf = frag_ld<ROWBV>(vs, (u32)(mi2*16 + ql), (u32)(psl*64 + h*16));
        accX[mi2] = mfma16(vf, pb.v, accX[mi2]);
      }
    }

    // drain the 2 staging loads, leave the MI attention stores in flight
    barrier_vmleave<MI>();
  }

  // write x^T to concat buffer: accX[mi2][r] = x[d = mi2*16+4h+r][q]
  u32 col0 = (batch & ((1u<<BSHIFT)-1u)) * (u32)D + xcolAdd;
  #pragma unroll
  for (int mi2=0; mi2<MIPV; ++mi2){
    union { f16_t v[4]; uint64_t u; } pk4;
    #pragma unroll
    for (int r=0;r<4;++r) pk4.v[r] = (f16_t)accX[mi2][r];
    *reinterpret_cast<uint64_t*>(xout + ((size_t)bb*S + q)*xld + col0 + mi2*16 + h*4) = pk4.u;
  }
}

// ---------------- combined attention kernel ----------------
// XCD-aware remap: blockIdx.x (=XCD via %8 round-robin) owns 17 whole heads;
// all 8 q-tiles of one head land on the SAME XCD -> K/V L2-resident.
__global__ __launch_bounds__(512, 4)
void attn_all(const f16_t* __restrict__ Qh, const f16_t* __restrict__ Kh,
              const f16_t* __restrict__ Vth, const float* __restrict__ mbias,
              float* __restrict__ attnp,
              const f16_t* __restrict__ xrf, const f16_t* __restrict__ strK,
              const f16_t* __restrict__ strVt, const float* __restrict__ rbias,
              float* __restrict__ rsap,
              f16_t* __restrict__ conc)
{
  __shared__ char smem[65536];
  const int tid = threadIdx.x;
  const u32 qt = blockIdx.y & 7u;
  const u32 bh = blockIdx.x * 17u + (blockIdx.y >> 3);
  if (bh < 8u) attn_fused_body<128,32,0,0>(smem, xrf, strK, strVt, rbias, rsap, conc, 1152u, 1024u, tid, qt, bh);
  else         attn_fused_body<64, 64,4,1>(smem, Qh,  Kh,   Vth,   mbias, attnp, conc, 1152u, 0u,    tid, qt, bh-8u);
}

// ---------------- launch ----------------
extern "C" void kernel_launch(void* const* d_in, const int* in_sizes, int n_in,
                              void* d_out, int out_size, void* d_ws, size_t ws_size,
                              hipStream_t stream)
{
  const float* query = (const float*)d_in[0];
  const float* key   = (const float*)d_in[1];
  const float* value = (const float*)d_in[2];
  const float* x_rsa = (const float*)d_in[3];
  const int*   mask  = (const int*)d_in[4];
  const int*   rmask = (const int*)d_in[5];
  const float* Wq = (const float*)d_in[6];  const float* bq = (const float*)d_in[7];
  const float* Wk = (const float*)d_in[8];  const float* bk = (const float*)d_in[9];
  const float* Wv = (const float*)d_in[10]; const float* bv = (const float*)d_in[11];
  const float* Wsk= (const float*)d_in[12]; const float* bsk= (const float*)d_in[13];
  const float* Wsv= (const float*)d_in[14]; const float* bsv= (const float*)d_in[15];
  const float* Wo = (const float*)d_in[16]; const float* bo = (const float*)d_in[17];

  char* ws = (char*)d_ws;
  size_t off = 0;
  auto alloc = [&](size_t bytes)->char*{ char* p = ws + off; off += (bytes + 255) & ~(size_t)255; return p; };

  f16_t* q16  = (f16_t*)alloc(16777216);
  f16_t* k16  = (f16_t*)alloc(16777216);
  f16_t* v16  = (f16_t*)alloc(16777216);
  f16_t* xrf  = (f16_t*)alloc(2097152);
  f16_t* wqT  = (f16_t*)alloc(2097152);
  f16_t* wkT  = (f16_t*)alloc(2097152);
  f16_t* wvT  = (f16_t*)alloc(2097152);
  f16_t* wskT = (f16_t*)alloc(262144);
  f16_t* wsvT = (f16_t*)alloc(262144);
  f16_t* woT  = (f16_t*)alloc(2359296);
  f16_t* Qh   = (f16_t*)alloc(16777216);
  f16_t* Kh   = (f16_t*)alloc(16777216);
  f16_t* Vth  = (f16_t*)alloc(16777216);
  f16_t* strK = (f16_t*)alloc(2097152);
  f16_t* strVt= (f16_t*)alloc(2097152);
  f16_t* conc = (f16_t*)alloc(18874368);
  float* mbias= (float*)alloc(32768);
  float* rbias= (float*)alloc(32768);

  // prep: converts + mask biases + weight transposes, one launch
  prep_all<<<17312,256,0,stream>>>(query, key, value, x_rsa, mask, rmask,
                                   q16, k16, v16, xrf, mbias, rbias,
                                   Wq, Wk, Wv, Wsk, Wsv, Wo,
                                   wqT, wkT, wvT, wskT, wsvT, woT);

  // all input projections in one launch: z=0 -> str (bx 0/1), z=1..3 -> Q/K/V
  {
    GPack pm{};
    pm.g[0] = {q16, wqT,  bq,  (void*)Qh,    1024u,1024u,0u,   1024u, 1};
    pm.g[1] = {k16, wkT,  bk,  (void*)Kh,    1024u,1024u,0u,   1024u, 1};
    pm.g[2] = {v16, wvT,  bv,  (void*)Vth,   1024u,1024u,1024u,1024u, 2};
    pm.g[3] = {k16, wskT, bsk, (void*)strK,  1024u,1024u,128u, 1024u, 3};
    pm.g[4] = {v16, wsvT, bsv, (void*)strVt, 1024u,1024u,128u, 1024u, 2};
    pm.single = -1;
    gemm_bt<<<dim3(8,64,4),256,0,stream>>>(pm);
  }

  float* outp  = (float*)d_out;
  float* attnp = outp + 8388608;
  float* rsap  = outp + 8388608 + 134217728;

  // fused attention (row-sums + softmax store + PV into concat), one launch
  attn_all<<<dim3(8,136),512,0,stream>>>(Qh, Kh, Vth, mbias, attnp,
                                         xrf, strK, strVt, rbias, rsap, conc);

  // output projection
  {
    GPack po{};
    po.g[0] = {conc, woT, bo, (void*)outp, 1152u,1152u,1024u,1152u, 0};
    po.g[1] = po.g[0]; po.g[2] = po.g[0]; po.g[3] = po.g[0]; po.g[4] = po.g[0];
    po.single = 0;
    gemm_bt<<<dim3(8,64,1),256,0,stream>>>(po);
  }

  (void)in_sizes; (void)n_in; (void)out_size; (void)ws_size;
}